// Round 2
// baseline (1429.408 us; speedup 1.0000x reference)
//
#include <hip/hip_runtime.h>
#include <math.h>

// Problem constants
#define BATCH  128
#define NIN    1152
#define DIN    8
#define NOUTC  10
#define DOUT   16
#define H1DIM  512
#define H2DIM  1024
#define PIX    784
#define NROWS  (BATCH * NOUTC)   // 1280

typedef __attribute__((ext_vector_type(8))) __bf16 bf16x8;
typedef __attribute__((ext_vector_type(4))) float  f32x4;

__device__ __forceinline__ float bf2f(ushort u) {
    union { unsigned int i; float f; } v; v.i = ((unsigned int)u) << 16; return v.f;
}
__device__ __forceinline__ ushort f2bf(float f) {
    union { float f; unsigned int i; } v; v.f = f;
    unsigned int r = v.i + 0x7FFFu + ((v.i >> 16) & 1u);
    return (ushort)(r >> 16);
}
// dtype-agnostic input load (isbf uniform per kernel -> no divergence)
__device__ __forceinline__ float ldin(const void* p, size_t i, int isbf) {
    return isbf ? bf2f(((const ushort*)p)[i]) : ((const float*)p)[i];
}
__device__ __forceinline__ bf16x8 ld_frag(const ushort* p) {
    uint4 u = *(const uint4*)p;
    return __builtin_bit_cast(bf16x8, u);
}

// ---------------------------------------------------------------------------
// dtype probe: even ushort indices of `weight` are genuine bf16 values if the
// tensor is bf16 (sane exponents), or random mantissa bits if it is f32.
// ---------------------------------------------------------------------------
__global__ __launch_bounds__(256) void detect_kernel(const void* w, int* flag)
{
    __shared__ int cnt;
    if (threadIdx.x == 0) cnt = 0;
    __syncthreads();
    const ushort* u = (const ushort*)w;
    int c = 0;
    for (int s = threadIdx.x; s < 512; s += 256) {
        int e = (u[s * 2] >> 7) & 0xFF;
        if (e >= 88 && e <= 140) c++;
    }
    atomicAdd(&cnt, c);
    __syncthreads();
    if (threadIdx.x == 0) *flag = (cnt >= 384) ? 1 : 0;
}

// ---------------------------------------------------------------------------
// routing_pass: one block per (b,n). Recomputes hat[b,n,:,:] into LDS (bf16),
// rc-weighted k-sum -> squash -> outcaps; then bscore[k] = <outcaps, hat_k>.
// iter0: rc == 1. If outFinal != null writes final output (dtype per flag).
// ---------------------------------------------------------------------------
__global__ __launch_bounds__(256) void routing_pass(
    const void*   __restrict__ incaps,   // (B, NIN, DIN)
    const void*   __restrict__ weight,   // (NOUTC, NIN, DOUT, DIN)
    const ushort* __restrict__ cbuf,     // (B*NOUTC, NIN) bf16 coefficients
    const float*  __restrict__ rWS,      // (B*NOUTC) f32
    const int*    __restrict__ flagp,
    int iter0,
    float*  __restrict__ outcapsWS,      // (B*NOUTC, DOUT) f32
    ushort* __restrict__ bscore_out,     // (B*NOUTC, NIN) bf16 (may be null)
    void*   __restrict__ outFinal)       // final output (may be null)
{
    int bn  = blockIdx.x;            // b*10 + n
    int n   = bn % NOUTC;
    int b   = bn / NOUTC;
    int tid = threadIdx.x;
    int isbf = *flagp;

    __shared__ ushort incS[NIN * DIN];    // 18 KB
    __shared__ ushort hatS[NIN * DOUT];   // 36 KB
    __shared__ float  wS[NIN];            // 4.6 KB
    __shared__ float  redS[16][16];
    __shared__ float  sumS[16];
    __shared__ float  ocS[16];
    __shared__ float  scaleS;

    // stage incaps[b] (scalar loads: alignment-safe, dtype-safe)
    size_t ibase = (size_t)b * NIN * DIN;
    for (int i = tid; i < NIN * DIN; i += 256)
        incS[i] = f2bf(ldin(incaps, ibase + i, isbf));
    // stage rc weights
    float rv = iter0 ? 1.f : rWS[bn];
    for (int k = tid; k < NIN; k += 256)
        wS[k] = iter0 ? 1.f : bf2f(cbuf[(size_t)bn * NIN + k]) * rv;
    __syncthreads();

    // hat[k][o] = sum_i W[n][k][o][i] * inc[k][i]
    size_t wbase = (size_t)n * NIN * DOUT * DIN;
    for (int idx = tid; idx < NIN * DOUT; idx += 256) {
        int k = idx >> 4;
        size_t w8 = wbase + (size_t)idx * 8;
        const ushort* i8 = incS + k * 8;
        float s = 0.f;
        #pragma unroll
        for (int i = 0; i < 8; i++) s += ldin(weight, w8 + i, isbf) * bf2f(i8[i]);
        hatS[idx] = f2bf(s);
    }
    __syncthreads();

    // weighted sum over k: thread (g,o) sums k = g, g+16, ...
    int o16 = tid & 15, g16 = tid >> 4;
    float part = 0.f;
    for (int k = g16; k < NIN; k += 16)
        part += wS[k] * bf2f(hatS[k * 16 + o16]);
    redS[g16][o16] = part;
    __syncthreads();
    if (tid < 16) {
        float s = 0.f;
        #pragma unroll
        for (int g = 0; g < 16; g++) s += redS[g][tid];
        sumS[tid] = s;
    }
    __syncthreads();
    if (tid == 0) {
        float n2 = 0.f;
        #pragma unroll
        for (int o = 0; o < 16; o++) n2 += sumS[o] * sumS[o];
        float nrm = sqrtf(n2);
        scaleS = n2 / (1.f + n2) / (nrm + 1e-8f);
    }
    __syncthreads();
    if (tid < 16) {
        float oc = scaleS * sumS[tid];
        ocS[tid] = oc;
        outcapsWS[(size_t)bn * 16 + tid] = oc;
        if (outFinal) {
            if (isbf) ((ushort*)outFinal)[(size_t)bn * 16 + tid] = f2bf(oc);
            else      ((float*) outFinal)[(size_t)bn * 16 + tid] = oc;
        }
    }
    __syncthreads();

    if (bscore_out) {
        for (int k = tid; k < NIN; k += 256) {
            const ushort* h = hatS + k * 16;
            float s = 0.f;
            #pragma unroll
            for (int o = 0; o < 16; o++) s += ocS[o] * bf2f(h[o]);
            bscore_out[(size_t)bn * NIN + k] = f2bf(s);
        }
    }
}

// ---------------------------------------------------------------------------
// scale_coef over classes, in place on the bf16 bscore buffer. Thread per (b,k).
// ---------------------------------------------------------------------------
__global__ __launch_bounds__(256) void coef_kernel(ushort* __restrict__ cbuf)
{
    int idx = blockIdx.x * 256 + threadIdx.x;   // grid covers B*NIN exactly
    int b = idx / NIN, k = idx % NIN;
    ushort* col = cbuf + (size_t)b * NOUTC * NIN + k;
    float v[9], mn = 1e30f, mx = -1e30f;
    #pragma unroll
    for (int n = 0; n < 9; n++) {
        v[n] = bf2f(col[(size_t)n * NIN]);
        mn = fminf(mn, v[n]); mx = fmaxf(mx, v[n]);
    }
    float denom = fmaxf(mx - mn, 1e-6f);
    #pragma unroll
    for (int n = 0; n < 9; n++)
        col[(size_t)n * NIN] = f2bf(fmaxf((v[n] - mn) / denom, 0.5f));
    col[(size_t)9 * NIN] = f2bf(0.5f);
}

// scale_coef for rscore -> r. One thread per batch element.
__global__ __launch_bounds__(128) void r_kernel(
    const float* __restrict__ rscore, float* __restrict__ rWS)
{
    int b = threadIdx.x;
    float v[9], mn = 1e30f, mx = -1e30f;
    #pragma unroll
    for (int n = 0; n < 9; n++) {
        v[n] = rscore[b * NOUTC + n];
        mn = fminf(mn, v[n]); mx = fmaxf(mx, v[n]);
    }
    float denom = fmaxf(mx - mn, 1e-6f);
    #pragma unroll
    for (int n = 0; n < 9; n++)
        rWS[b * NOUTC + n] = fmaxf((v[n] - mn) / denom, 0.5f);
    rWS[b * NOUTC + 9] = 0.5f;
}

// ---------------------------------------------------------------------------
// Decoder layer 1: masked input is block-diagonal -> 16-wide dot per row.
// ---------------------------------------------------------------------------
__global__ __launch_bounds__(128) void layer1_kernel(
    const float* __restrict__ outcapsWS, const void* __restrict__ W1,
    const void* __restrict__ b1, const int* __restrict__ flagp,
    ushort* __restrict__ h1)
{
    int row = blockIdx.x;
    int n = row % NOUTC;
    int tid = threadIdx.x;
    int isbf = *flagp;
    __shared__ float oc[16];
    if (tid < 16) oc[tid] = outcapsWS[(size_t)row * 16 + tid];
    __syncthreads();
    for (int col = tid; col < H1DIM; col += 128) {
        float acc = ldin(b1, col, isbf);
        #pragma unroll
        for (int i = 0; i < 16; i++)
            acc += oc[i] * ldin(W1, (size_t)(n * 16 + i) * H1DIM + col, isbf);
        h1[(size_t)row * H1DIM + col] = f2bf(fmaxf(acc, 0.f));
    }
}

// ---------------------------------------------------------------------------
// tile transpose (R x C -> C x R), dtype-agnostic in, bf16 out
// ---------------------------------------------------------------------------
__global__ __launch_bounds__(256) void transpose_kernel(
    const void* __restrict__ in, const int* __restrict__ flagp,
    ushort* __restrict__ out, int R, int C)
{
    __shared__ ushort tile[32][33];
    int isbf = *flagp;
    int c0 = blockIdx.x * 32, r0 = blockIdx.y * 32;
    int tx = threadIdx.x & 31, ty = threadIdx.x >> 5;
    for (int i = ty; i < 32; i += 8) {
        int r = r0 + i, c = c0 + tx;
        tile[i][tx] = (r < R && c < C) ? f2bf(ldin(in, (size_t)r * C + c, isbf)) : (ushort)0;
    }
    __syncthreads();
    for (int i = ty; i < 32; i += 8) {
        int c = c0 + i, r = r0 + tx;
        if (c < C && r < R) out[(size_t)c * R + r] = tile[tx][i];
    }
}

// ---------------------------------------------------------------------------
// 64x64-tile MFMA GEMM: C = act(A @ Bt^T + bias).
// A: M x K bf16 (ours), Bt: N x K bf16 (ours). Cout!=null: ReLU, bf16 (layer2).
// Else: fused sigmoid + squared-error vs x, atomicAdd into rscore (layer 3).
// ---------------------------------------------------------------------------
__global__ __launch_bounds__(256) void gemm_kernel(
    const ushort* __restrict__ A, const ushort* __restrict__ Bt,
    const void* __restrict__ bias, const int* __restrict__ flagp,
    int K, int N,
    ushort* __restrict__ Cout,
    const void* __restrict__ xin, float* __restrict__ rscore)
{
    int m0 = blockIdx.x * 64, n0 = blockIdx.y * 64;
    int tid = threadIdx.x;
    int wave = tid >> 6, lane = tid & 63, quad = lane >> 4, l16 = lane & 15;
    int isbf = *flagp;

    __shared__ uint4 AsB[256];   // 64 x 32 bf16
    __shared__ uint4 BsB[256];   // 64 x 32 bf16 (rows of Bt)
    ushort* As = (ushort*)AsB;
    ushort* Bs = (ushort*)BsB;

    f32x4 acc[4];
    #pragma unroll
    for (int nt = 0; nt < 4; nt++)
        #pragma unroll
        for (int rg = 0; rg < 4; rg++) acc[nt][rg] = 0.f;

    int sIdx = tid * 8;
    int sMi = sIdx >> 5, sKk = sIdx & 31;

    for (int k0 = 0; k0 < K; k0 += 32) {
        *(uint4*)(As + sIdx) = *(const uint4*)(A + (size_t)(m0 + sMi) * K + k0 + sKk);
        uint4 bv = make_uint4(0, 0, 0, 0);
        if (n0 + sMi < N) bv = *(const uint4*)(Bt + (size_t)(n0 + sMi) * K + k0 + sKk);
        *(uint4*)(Bs + sIdx) = bv;
        __syncthreads();

        bf16x8 a = ld_frag(As + (wave * 16 + l16) * 32 + quad * 8);
        #pragma unroll
        for (int nt = 0; nt < 4; nt++) {
            bf16x8 bb = ld_frag(Bs + (nt * 16 + l16) * 32 + quad * 8);
            acc[nt] = __builtin_amdgcn_mfma_f32_16x16x32_bf16(a, bb, acc[nt], 0, 0, 0);
        }
        __syncthreads();
    }

    int rowBase = m0 + wave * 16 + quad * 4;
    if (Cout) {
        #pragma unroll
        for (int nt = 0; nt < 4; nt++) {
            int col = n0 + nt * 16 + l16;
            float bv = ldin(bias, col, isbf);
            #pragma unroll
            for (int rg = 0; rg < 4; rg++) {
                float v = acc[nt][rg] + bv;
                Cout[(size_t)(rowBase + rg) * N + col] = f2bf(fmaxf(v, 0.f));
            }
        }
    } else {
        float vr[4] = {0.f, 0.f, 0.f, 0.f};
        #pragma unroll
        for (int nt = 0; nt < 4; nt++) {
            int col = n0 + nt * 16 + l16;
            if (col < N) {
                float bv = ldin(bias, col, isbf);
                #pragma unroll
                for (int rg = 0; rg < 4; rg++) {
                    int row = rowBase + rg;
                    int bb = row / NOUTC;
                    float z = acc[nt][rg] + bv;
                    float s = 1.f / (1.f + __expf(-z));
                    float d = ldin(xin, (size_t)bb * PIX + col, isbf) - s;
                    vr[rg] += d * d;
                }
            }
        }
        #pragma unroll
        for (int rg = 0; rg < 4; rg++) {
            float v = vr[rg];
            #pragma unroll
            for (int off = 8; off >= 1; off >>= 1) v += __shfl_xor(v, off, 16);
            if (l16 == 0) atomicAdd(&rscore[rowBase + rg], -v);
        }
    }
}

// ---------------------------------------------------------------------------
extern "C" void kernel_launch(void* const* d_in, const int* in_sizes, int n_in,
                              void* d_out, int out_size, void* d_ws, size_t ws_size,
                              hipStream_t stream)
{
    const void* inc = d_in[0];   // (128,1152,8)
    const void* x   = d_in[1];   // (128,1,28,28)
    const void* w   = d_in[2];   // (10,1152,16,8)
    const void* W1  = d_in[3];   // (160,512)
    const void* b1  = d_in[4];   // (512)
    const void* W2  = d_in[5];   // (512,1024)
    const void* b2  = d_in[6];   // (1024)
    const void* W3  = d_in[7];   // (1024,784)
    const void* b3  = d_in[8];   // (784)

    char* p = (char*)d_ws;
    auto alloc = [&](size_t bytes) { void* r = p; p += (bytes + 255) & ~(size_t)255; return r; };
    int*    flagWS    = (int*)alloc(256);
    float*  outcapsWS = (float*)alloc((size_t)NROWS * 16 * 4);
    ushort* cbuf      = (ushort*)alloc((size_t)NROWS * NIN * 2);  // bscore -> c, in place
    float*  rWS       = (float*)alloc((size_t)NROWS * 4);
    float*  rscoreWS  = (float*)alloc((size_t)NROWS * 4);
    ushort* h1WS      = (ushort*)alloc((size_t)NROWS * H1DIM * 2);
    ushort* h2WS      = (ushort*)alloc((size_t)NROWS * H2DIM * 2);
    ushort* W2T       = (ushort*)alloc((size_t)H2DIM * H1DIM * 2);
    ushort* W3T       = (ushort*)alloc((size_t)PIX * H2DIM * 2);
    // total ~9.6 MB

    detect_kernel<<<1, 256, 0, stream>>>(w, flagWS);

    // pre-transpose decoder weights (B^T layout for MFMA fragment loads)
    transpose_kernel<<<dim3(32, 16), 256, 0, stream>>>(W2, flagWS, W2T, H1DIM, H2DIM);
    transpose_kernel<<<dim3(25, 32), 256, 0, stream>>>(W3, flagWS, W3T, H2DIM, PIX);

    for (int it = 0; it < 2; it++) {
        routing_pass<<<NROWS, 256, 0, stream>>>(inc, w, cbuf, rWS, flagWS,
                                                it == 0 ? 1 : 0,
                                                outcapsWS, cbuf, nullptr);
        coef_kernel<<<(BATCH * NIN) / 256, 256, 0, stream>>>(cbuf);
        layer1_kernel<<<NROWS, 128, 0, stream>>>(outcapsWS, W1, b1, flagWS, h1WS);
        gemm_kernel<<<dim3(NROWS / 64, H2DIM / 64), 256, 0, stream>>>(
            h1WS, W2T, b2, flagWS, H1DIM, H2DIM, h2WS, nullptr, nullptr);
        hipMemsetAsync(rscoreWS, 0, (size_t)NROWS * 4, stream);
        gemm_kernel<<<dim3(NROWS / 64, (PIX + 63) / 64), 256, 0, stream>>>(
            h2WS, W3T, b3, flagWS, H2DIM, PIX, nullptr, x, rscoreWS);
        r_kernel<<<1, 128, 0, stream>>>(rscoreWS, rWS);
    }
    routing_pass<<<NROWS, 256, 0, stream>>>(inc, w, cbuf, rWS, flagWS, 0,
                                            outcapsWS, nullptr, d_out);
}

// Round 3
// 288.437 us; speedup vs baseline: 4.9557x; 4.9557x over previous
//
#include <hip/hip_runtime.h>
#include <math.h>

// Problem constants
#define BATCH  128
#define NIN    1152
#define DIN    8
#define NOUTC  10
#define DOUT   16
#define H1DIM  512
#define H2DIM  1024
#define PIX    784
#define NROWS  (BATCH * NOUTC)   // 1280

typedef __attribute__((ext_vector_type(8))) __bf16 bf16x8;
typedef __attribute__((ext_vector_type(4))) float  f32x4;

__device__ __forceinline__ float bf2f(unsigned int u) {
    union { unsigned int i; float f; } v; v.i = u << 16; return v.f;
}
__device__ __forceinline__ ushort f2bf(float f) {
    union { float f; unsigned int i; } v; v.f = f;
    unsigned int r = v.i + 0x7FFFu + ((v.i >> 16) & 1u);
    return (ushort)(r >> 16);
}
// dtype-agnostic input load (isbf uniform per kernel)
__device__ __forceinline__ float ldin(const void* p, size_t i, int isbf) {
    return isbf ? bf2f(((const ushort*)p)[i]) : ((const float*)p)[i];
}
__device__ __forceinline__ bf16x8 ld_frag(const ushort* p) {
    uint4 u = *(const uint4*)p;
    return __builtin_bit_cast(bf16x8, u);
}
// dot product of two packed-bf16x8 uint4s, fp32 accum
__device__ __forceinline__ float dot8(uint4 a, uint4 b) {
    float s;
    s  = bf2f(a.x & 0xffffu) * bf2f(b.x & 0xffffu);
    s += bf2f(a.x >> 16)     * bf2f(b.x >> 16);
    s += bf2f(a.y & 0xffffu) * bf2f(b.y & 0xffffu);
    s += bf2f(a.y >> 16)     * bf2f(b.y >> 16);
    s += bf2f(a.z & 0xffffu) * bf2f(b.z & 0xffffu);
    s += bf2f(a.z >> 16)     * bf2f(b.z >> 16);
    s += bf2f(a.w & 0xffffu) * bf2f(b.w & 0xffffu);
    s += bf2f(a.w >> 16)     * bf2f(b.w >> 16);
    return s;
}

// ---------------------------------------------------------------------------
// dtype probe: even ushort indices of `weight` are genuine bf16 values if the
// tensor is bf16 (sane exponents), or random mantissa bits if it is f32.
// ---------------------------------------------------------------------------
__global__ __launch_bounds__(256) void detect_kernel(const void* w, int* flag)
{
    __shared__ int cnt;
    if (threadIdx.x == 0) cnt = 0;
    __syncthreads();
    const ushort* u = (const ushort*)w;
    int c = 0;
    for (int s = threadIdx.x; s < 512; s += 256) {
        int e = (u[s * 2] >> 7) & 0xFF;
        if (e >= 88 && e <= 140) c++;
    }
    atomicAdd(&cnt, c);
    __syncthreads();
    if (threadIdx.x == 0) *flag = (cnt >= 384) ? 1 : 0;
}

// ---------------------------------------------------------------------------
// convert any input tensor to bf16 (identity copy when already bf16)
// ---------------------------------------------------------------------------
__global__ __launch_bounds__(256) void cvt_kernel(
    const void* __restrict__ src, ushort* __restrict__ dst, int n,
    const int* __restrict__ flagp)
{
    int isbf = *flagp;
    int stride = gridDim.x * 256;
    if (isbf) {
        const ushort* s = (const ushort*)src;
        for (int i = blockIdx.x * 256 + threadIdx.x; i < n; i += stride)
            dst[i] = s[i];
    } else {
        const float* s = (const float*)src;
        for (int i = blockIdx.x * 256 + threadIdx.x; i < n; i += stride)
            dst[i] = f2bf(s[i]);
    }
}

// ---------------------------------------------------------------------------
// routing_pass: one block per (b,n).
// COMPUTE=true : build hat[bn] in LDS from wcvt/icvt (vectorized), optionally
//                stream it to hatG.
// COMPUTE=false: stage hat[bn] from hatG (uint4, coalesced).
// Then: rc-weighted k-sum -> squash -> outcaps; bscore[k] = <outcaps, hat_k>.
// ---------------------------------------------------------------------------
template<bool COMPUTE>
__global__ __launch_bounds__(256) void routing_pass(
    const ushort* __restrict__ icvt,     // (B, NIN, DIN) bf16
    const ushort* __restrict__ wcvt,     // (NOUTC, NIN, DOUT, DIN) bf16
    ushort* __restrict__ hatG,           // (B*NOUTC, NIN, DOUT) bf16
    const ushort* __restrict__ cbuf,     // (B*NOUTC, NIN) bf16 coefficients
    const float*  __restrict__ rWS,      // (B*NOUTC) f32
    int iter0,
    float*  __restrict__ outcapsWS,      // (B*NOUTC, DOUT) f32
    ushort* __restrict__ bscore_out,     // (B*NOUTC, NIN) bf16 (may be null)
    void*   __restrict__ outFinal,       // final output (may be null)
    const int* __restrict__ flagp)
{
    int bn  = blockIdx.x;            // b*10 + n
    int n   = bn % NOUTC;
    int b   = bn / NOUTC;
    int tid = threadIdx.x;

    __shared__ ushort hatS[NIN * DOUT];   // 36 KB
    __shared__ float  wS[NIN];            // 4.6 KB
    __shared__ float  redS[16][16];
    __shared__ float  sumS[16];
    __shared__ float  ocS[16];
    __shared__ float  scaleS;

    // stage rc weights
    if (!iter0) {
        float rv = rWS[bn];
        for (int k = tid; k < NIN; k += 256)
            wS[k] = bf2f(cbuf[(size_t)bn * NIN + k]) * rv;
    } else {
        for (int k = tid; k < NIN; k += 256) wS[k] = 1.f;
    }

    if (COMPUTE) {
        __shared__ ushort incS[NIN * DIN];   // 18 KB
        // stage incaps[b] (uint4, coalesced)
        const uint4* incp = (const uint4*)(icvt + (size_t)b * NIN * DIN);
        uint4* incS4 = (uint4*)incS;
        for (int i = tid; i < NIN * DIN / 8; i += 256) incS4[i] = incp[i];
        __syncthreads();

        // hat[k][o] = <W[n][k][o][:], inc[k][:]>  (one uint4 each side)
        const ushort* wp = wcvt + (size_t)n * NIN * DOUT * DIN;
        for (int idx = tid; idx < NIN * DOUT; idx += 256) {
            int k = idx >> 4;
            uint4 wu = *(const uint4*)(wp + (size_t)idx * 8);
            uint4 iu = *(const uint4*)(incS + k * 8);
            hatS[idx] = f2bf(dot8(wu, iu));
        }
        __syncthreads();
        if (hatG) {  // stream hat tile to global for later iterations
            uint4* hg = (uint4*)(hatG + (size_t)bn * NIN * DOUT);
            const uint4* hs = (const uint4*)hatS;
            for (int i = tid; i < NIN * DOUT / 8; i += 256) hg[i] = hs[i];
        }
    } else {
        const uint4* hp = (const uint4*)(hatG + (size_t)bn * NIN * DOUT);
        uint4* hs = (uint4*)hatS;
        for (int i = tid; i < NIN * DOUT / 8; i += 256) hs[i] = hp[i];
        __syncthreads();
    }

    // weighted sum over k: thread (g,o) sums k = g, g+16, ... (conflict-free)
    int o16 = tid & 15, g16 = tid >> 4;
    float part = 0.f;
    for (int k = g16; k < NIN; k += 16)
        part += wS[k] * bf2f(hatS[k * 16 + o16]);
    redS[g16][o16] = part;
    __syncthreads();
    if (tid < 16) {
        float s = 0.f;
        #pragma unroll
        for (int g = 0; g < 16; g++) s += redS[g][tid];
        sumS[tid] = s;
    }
    __syncthreads();
    if (tid == 0) {
        float n2 = 0.f;
        #pragma unroll
        for (int o = 0; o < 16; o++) n2 += sumS[o] * sumS[o];
        float nrm = sqrtf(n2);
        scaleS = n2 / (1.f + n2) / (nrm + 1e-8f);
    }
    __syncthreads();
    if (tid < 16) {
        float oc = scaleS * sumS[tid];
        ocS[tid] = oc;
        outcapsWS[(size_t)bn * 16 + tid] = oc;
        if (outFinal) {
            if (*flagp) ((ushort*)outFinal)[(size_t)bn * 16 + tid] = f2bf(oc);
            else        ((float*) outFinal)[(size_t)bn * 16 + tid] = oc;
        }
    }
    __syncthreads();

    if (bscore_out) {
        for (int k = tid; k < NIN; k += 256) {
            bf16x8 h0 = ld_frag(hatS + k * 16);
            bf16x8 h1 = ld_frag(hatS + k * 16 + 8);
            float s = 0.f;
            #pragma unroll
            for (int o = 0; o < 8; o++) s += ocS[o] * (float)h0[o];
            #pragma unroll
            for (int o = 0; o < 8; o++) s += ocS[8 + o] * (float)h1[o];
            bscore_out[(size_t)bn * NIN + k] = f2bf(s);
        }
    }
}

// ---------------------------------------------------------------------------
// scale_coef over classes, in place on the bf16 bscore buffer. Thread per (b,k).
// ---------------------------------------------------------------------------
__global__ __launch_bounds__(256) void coef_kernel(ushort* __restrict__ cbuf)
{
    int idx = blockIdx.x * 256 + threadIdx.x;   // grid covers B*NIN exactly
    int b = idx / NIN, k = idx % NIN;
    ushort* col = cbuf + (size_t)b * NOUTC * NIN + k;
    float v[9], mn = 1e30f, mx = -1e30f;
    #pragma unroll
    for (int n = 0; n < 9; n++) {
        v[n] = bf2f(col[(size_t)n * NIN]);
        mn = fminf(mn, v[n]); mx = fmaxf(mx, v[n]);
    }
    float denom = fmaxf(mx - mn, 1e-6f);
    #pragma unroll
    for (int n = 0; n < 9; n++)
        col[(size_t)n * NIN] = f2bf(fmaxf((v[n] - mn) / denom, 0.5f));
    col[(size_t)9 * NIN] = f2bf(0.5f);
}

// scale_coef for rscore -> r. One thread per batch element.
__global__ __launch_bounds__(128) void r_kernel(
    const float* __restrict__ rscore, float* __restrict__ rWS)
{
    int b = threadIdx.x;
    float v[9], mn = 1e30f, mx = -1e30f;
    #pragma unroll
    for (int n = 0; n < 9; n++) {
        v[n] = rscore[b * NOUTC + n];
        mn = fminf(mn, v[n]); mx = fmaxf(mx, v[n]);
    }
    float denom = fmaxf(mx - mn, 1e-6f);
    #pragma unroll
    for (int n = 0; n < 9; n++)
        rWS[b * NOUTC + n] = fmaxf((v[n] - mn) / denom, 0.5f);
    rWS[b * NOUTC + 9] = 0.5f;
}

// ---------------------------------------------------------------------------
// Decoder layer 1: masked input is block-diagonal -> 16-wide dot per row.
// ---------------------------------------------------------------------------
__global__ __launch_bounds__(128) void layer1_kernel(
    const float* __restrict__ outcapsWS, const ushort* __restrict__ W1,
    const ushort* __restrict__ b1, ushort* __restrict__ h1)
{
    int row = blockIdx.x;
    int n = row % NOUTC;
    int tid = threadIdx.x;
    __shared__ float oc[16];
    if (tid < 16) oc[tid] = outcapsWS[(size_t)row * 16 + tid];
    __syncthreads();
    for (int col = tid; col < H1DIM; col += 128) {
        float acc = bf2f(b1[col]);
        #pragma unroll
        for (int i = 0; i < 16; i++)
            acc += oc[i] * bf2f(W1[(size_t)(n * 16 + i) * H1DIM + col]);
        h1[(size_t)row * H1DIM + col] = f2bf(fmaxf(acc, 0.f));
    }
}

// ---------------------------------------------------------------------------
// tile transpose (R x C -> C x R), dtype-agnostic in, bf16 out
// ---------------------------------------------------------------------------
__global__ __launch_bounds__(256) void transpose_kernel(
    const void* __restrict__ in, const int* __restrict__ flagp,
    ushort* __restrict__ out, int R, int C)
{
    __shared__ ushort tile[32][33];
    int isbf = *flagp;
    int c0 = blockIdx.x * 32, r0 = blockIdx.y * 32;
    int tx = threadIdx.x & 31, ty = threadIdx.x >> 5;
    for (int i = ty; i < 32; i += 8) {
        int r = r0 + i, c = c0 + tx;
        tile[i][tx] = (r < R && c < C) ? f2bf(ldin(in, (size_t)r * C + c, isbf)) : (ushort)0;
    }
    __syncthreads();
    for (int i = ty; i < 32; i += 8) {
        int c = c0 + i, r = r0 + tx;
        if (c < C && r < R) out[(size_t)c * R + r] = tile[tx][i];
    }
}

// ---------------------------------------------------------------------------
// 64x64-tile MFMA GEMM: C = act(A @ Bt^T + bias).
// A: M x K bf16, Bt: N x K bf16. Cout!=null: ReLU, bf16 (layer2).
// Else: fused sigmoid + squared-error vs x, atomicAdd into rscore (layer 3).
// ---------------------------------------------------------------------------
__global__ __launch_bounds__(256) void gemm_kernel(
    const ushort* __restrict__ A, const ushort* __restrict__ Bt,
    const ushort* __restrict__ bias, int K, int N,
    ushort* __restrict__ Cout,
    const ushort* __restrict__ xin, float* __restrict__ rscore)
{
    int m0 = blockIdx.x * 64, n0 = blockIdx.y * 64;
    int tid = threadIdx.x;
    int wave = tid >> 6, lane = tid & 63, quad = lane >> 4, l16 = lane & 15;

    __shared__ uint4 AsB[256];   // 64 x 32 bf16
    __shared__ uint4 BsB[256];   // 64 x 32 bf16 (rows of Bt)
    ushort* As = (ushort*)AsB;
    ushort* Bs = (ushort*)BsB;

    f32x4 acc[4];
    #pragma unroll
    for (int nt = 0; nt < 4; nt++)
        #pragma unroll
        for (int rg = 0; rg < 4; rg++) acc[nt][rg] = 0.f;

    int sIdx = tid * 8;
    int sMi = sIdx >> 5, sKk = sIdx & 31;

    for (int k0 = 0; k0 < K; k0 += 32) {
        *(uint4*)(As + sIdx) = *(const uint4*)(A + (size_t)(m0 + sMi) * K + k0 + sKk);
        uint4 bv = make_uint4(0, 0, 0, 0);
        if (n0 + sMi < N) bv = *(const uint4*)(Bt + (size_t)(n0 + sMi) * K + k0 + sKk);
        *(uint4*)(Bs + sIdx) = bv;
        __syncthreads();

        bf16x8 a = ld_frag(As + (wave * 16 + l16) * 32 + quad * 8);
        #pragma unroll
        for (int nt = 0; nt < 4; nt++) {
            bf16x8 bb = ld_frag(Bs + (nt * 16 + l16) * 32 + quad * 8);
            acc[nt] = __builtin_amdgcn_mfma_f32_16x16x32_bf16(a, bb, acc[nt], 0, 0, 0);
        }
        __syncthreads();
    }

    int rowBase = m0 + wave * 16 + quad * 4;
    if (Cout) {
        #pragma unroll
        for (int nt = 0; nt < 4; nt++) {
            int col = n0 + nt * 16 + l16;
            float bv = bf2f(bias[col]);
            #pragma unroll
            for (int rg = 0; rg < 4; rg++) {
                float v = acc[nt][rg] + bv;
                Cout[(size_t)(rowBase + rg) * N + col] = f2bf(fmaxf(v, 0.f));
            }
        }
    } else {
        float vr[4] = {0.f, 0.f, 0.f, 0.f};
        #pragma unroll
        for (int nt = 0; nt < 4; nt++) {
            int col = n0 + nt * 16 + l16;
            if (col < N) {
                float bv = bf2f(bias[col]);
                #pragma unroll
                for (int rg = 0; rg < 4; rg++) {
                    int row = rowBase + rg;
                    int bb = row / NOUTC;
                    float z = acc[nt][rg] + bv;
                    float s = 1.f / (1.f + __expf(-z));
                    float d = bf2f(xin[(size_t)bb * PIX + col]) - s;
                    vr[rg] += d * d;
                }
            }
        }
        #pragma unroll
        for (int rg = 0; rg < 4; rg++) {
            float v = vr[rg];
            #pragma unroll
            for (int off = 8; off >= 1; off >>= 1) v += __shfl_xor(v, off, 16);
            if (l16 == 0) atomicAdd(&rscore[rowBase + rg], -v);
        }
    }
}

// ---------------------------------------------------------------------------
extern "C" void kernel_launch(void* const* d_in, const int* in_sizes, int n_in,
                              void* d_out, int out_size, void* d_ws, size_t ws_size,
                              hipStream_t stream)
{
    const void* inc = d_in[0];   // (128,1152,8)
    const void* x   = d_in[1];   // (128,1,28,28)
    const void* w   = d_in[2];   // (10,1152,16,8)
    const void* W1  = d_in[3];   // (160,512)
    const void* b1  = d_in[4];   // (512)
    const void* W2  = d_in[5];   // (512,1024)
    const void* b2  = d_in[6];   // (1024)
    const void* W3  = d_in[7];   // (1024,784)
    const void* b3  = d_in[8];   // (784)

    char* p = (char*)d_ws;
    auto alloc = [&](size_t bytes) { void* r = p; p += (bytes + 255) & ~(size_t)255; return r; };
    int*    flagWS    = (int*)alloc(256);
    float*  outcapsWS = (float*)alloc((size_t)NROWS * 16 * 4);
    ushort* cbuf      = (ushort*)alloc((size_t)NROWS * NIN * 2);  // bscore -> c, in place
    float*  rWS       = (float*)alloc((size_t)NROWS * 4);
    float*  rscoreWS  = (float*)alloc((size_t)NROWS * 4);
    ushort* h1WS      = (ushort*)alloc((size_t)NROWS * H1DIM * 2);
    ushort* h2WS      = (ushort*)alloc((size_t)NROWS * H2DIM * 2);
    ushort* W2T       = (ushort*)alloc((size_t)H2DIM * H1DIM * 2);
    ushort* W3T       = (ushort*)alloc((size_t)PIX * H2DIM * 2);
    ushort* wcvt      = (ushort*)alloc((size_t)NOUTC * NIN * DOUT * DIN * 2);
    ushort* icvt      = (ushort*)alloc((size_t)BATCH * NIN * DIN * 2);
    ushort* W1c       = (ushort*)alloc((size_t)160 * H1DIM * 2);
    ushort* b1c       = (ushort*)alloc((size_t)H1DIM * 2);
    ushort* b2c       = (ushort*)alloc((size_t)H2DIM * 2);
    ushort* b3c       = (ushort*)alloc((size_t)PIX * 2);
    ushort* xc        = (ushort*)alloc((size_t)BATCH * PIX * 2);
    ushort* hatG      = (ushort*)alloc((size_t)NROWS * NIN * DOUT * 2);  // 47 MB, LAST
    bool haveHat = ((char*)hatG + (size_t)NROWS * NIN * DOUT * 2) <= ((char*)d_ws + ws_size);

    detect_kernel<<<1, 256, 0, stream>>>(w, flagWS);

    // one-time dtype normalization to bf16 workspace
    cvt_kernel<<<1024, 256, 0, stream>>>(w,  wcvt, NOUTC * NIN * DOUT * DIN, flagWS);
    cvt_kernel<<<1024, 256, 0, stream>>>(inc, icvt, BATCH * NIN * DIN, flagWS);
    cvt_kernel<<<320, 256, 0, stream>>>(W1, W1c, 160 * H1DIM, flagWS);
    cvt_kernel<<<2,   256, 0, stream>>>(b1, b1c, H1DIM, flagWS);
    cvt_kernel<<<4,   256, 0, stream>>>(b2, b2c, H2DIM, flagWS);
    cvt_kernel<<<4,   256, 0, stream>>>(b3, b3c, PIX, flagWS);
    cvt_kernel<<<392, 256, 0, stream>>>(x,  xc,  BATCH * PIX, flagWS);

    // pre-transpose decoder weights (B^T layout for MFMA fragment loads)
    transpose_kernel<<<dim3(32, 16), 256, 0, stream>>>(W2, flagWS, W2T, H1DIM, H2DIM);
    transpose_kernel<<<dim3(25, 32), 256, 0, stream>>>(W3, flagWS, W3T, H2DIM, PIX);

    for (int it = 0; it < 2; it++) {
        if (it == 0)
            routing_pass<true><<<NROWS, 256, 0, stream>>>(
                icvt, wcvt, haveHat ? hatG : nullptr, cbuf, rWS, 1,
                outcapsWS, cbuf, nullptr, flagWS);
        else if (haveHat)
            routing_pass<false><<<NROWS, 256, 0, stream>>>(
                icvt, wcvt, hatG, cbuf, rWS, 0,
                outcapsWS, cbuf, nullptr, flagWS);
        else
            routing_pass<true><<<NROWS, 256, 0, stream>>>(
                icvt, wcvt, nullptr, cbuf, rWS, 0,
                outcapsWS, cbuf, nullptr, flagWS);
        coef_kernel<<<(BATCH * NIN) / 256, 256, 0, stream>>>(cbuf);
        layer1_kernel<<<NROWS, 128, 0, stream>>>(outcapsWS, W1c, b1c, h1WS);
        gemm_kernel<<<dim3(NROWS / 64, H2DIM / 64), 256, 0, stream>>>(
            h1WS, W2T, b2c, H1DIM, H2DIM, h2WS, nullptr, nullptr);
        hipMemsetAsync(rscoreWS, 0, (size_t)NROWS * 4, stream);
        gemm_kernel<<<dim3(NROWS / 64, (PIX + 63) / 64), 256, 0, stream>>>(
            h2WS, W3T, b3c, H2DIM, PIX, nullptr, xc, rscoreWS);
        r_kernel<<<1, 128, 0, stream>>>(rscoreWS, rWS);
    }
    if (haveHat)
        routing_pass<false><<<NROWS, 256, 0, stream>>>(
            icvt, wcvt, hatG, cbuf, rWS, 0,
            outcapsWS, nullptr, d_out, flagWS);
    else
        routing_pass<true><<<NROWS, 256, 0, stream>>>(
            icvt, wcvt, nullptr, cbuf, rWS, 0,
            outcapsWS, nullptr, d_out, flagWS);
}

// Round 4
// 276.991 us; speedup vs baseline: 5.1605x; 1.0413x over previous
//
#include <hip/hip_runtime.h>
#include <math.h>

// Problem constants
#define BATCH  128
#define NIN    1152
#define DIN    8
#define NOUTC  10
#define DOUT   16
#define H1DIM  512
#define H2DIM  1024
#define PIX    784
#define NROWS  (BATCH * NOUTC)   // 1280

typedef __attribute__((ext_vector_type(8))) __bf16 bf16x8;
typedef __attribute__((ext_vector_type(4))) float  f32x4;

__device__ __forceinline__ float bf2f(unsigned int u) {
    union { unsigned int i; float f; } v; v.i = u << 16; return v.f;
}
__device__ __forceinline__ ushort f2bf(float f) {
    union { float f; unsigned int i; } v; v.f = f;
    unsigned int r = v.i + 0x7FFFu + ((v.i >> 16) & 1u);
    return (ushort)(r >> 16);
}
// dtype-agnostic input load (isbf uniform per kernel)
__device__ __forceinline__ float ldin(const void* p, size_t i, int isbf) {
    return isbf ? bf2f(((const ushort*)p)[i]) : ((const float*)p)[i];
}
__device__ __forceinline__ bf16x8 ld_frag(const ushort* p) {
    uint4 u = *(const uint4*)p;
    return __builtin_bit_cast(bf16x8, u);
}
// dot product of two packed-bf16x8 uint4s, fp32 accum
__device__ __forceinline__ float dot8(uint4 a, uint4 b) {
    float s;
    s  = bf2f(a.x & 0xffffu) * bf2f(b.x & 0xffffu);
    s += bf2f(a.x >> 16)     * bf2f(b.x >> 16);
    s += bf2f(a.y & 0xffffu) * bf2f(b.y & 0xffffu);
    s += bf2f(a.y >> 16)     * bf2f(b.y >> 16);
    s += bf2f(a.z & 0xffffu) * bf2f(b.z & 0xffffu);
    s += bf2f(a.z >> 16)     * bf2f(b.z >> 16);
    s += bf2f(a.w & 0xffffu) * bf2f(b.w & 0xffffu);
    s += bf2f(a.w >> 16)     * bf2f(b.w >> 16);
    return s;
}

// ---------------------------------------------------------------------------
// dtype probe: even ushort indices of `weight` are genuine bf16 values if the
// tensor is bf16 (sane exponents), or random mantissa bits if it is f32.
// ---------------------------------------------------------------------------
__global__ __launch_bounds__(256) void detect_kernel(const void* w, int* flag)
{
    __shared__ int cnt;
    if (threadIdx.x == 0) cnt = 0;
    __syncthreads();
    const ushort* u = (const ushort*)w;
    int c = 0;
    for (int s = threadIdx.x; s < 512; s += 256) {
        int e = (u[s * 2] >> 7) & 0xFF;
        if (e >= 88 && e <= 140) c++;
    }
    atomicAdd(&cnt, c);
    __syncthreads();
    if (threadIdx.x == 0) *flag = (cnt >= 384) ? 1 : 0;
}

// ---------------------------------------------------------------------------
// fused dtype normalization of all 7 small tensors (one launch)
// ---------------------------------------------------------------------------
struct CvtArgs { const void* src[7]; ushort* dst[7]; int n[7]; };

__global__ __launch_bounds__(256) void cvt_all(CvtArgs a, const int* __restrict__ flagp)
{
    int seg = blockIdx.y;
    int isbf = *flagp;
    int n = a.n[seg];
    int stride = gridDim.x * 256;
    int i0 = blockIdx.x * 256 + threadIdx.x;
    if (isbf) {
        const ushort* s = (const ushort*)a.src[seg];
        ushort* d = a.dst[seg];
        for (int i = i0; i < n; i += stride) d[i] = s[i];
    } else {
        const float* s = (const float*)a.src[seg];
        ushort* d = a.dst[seg];
        for (int i = i0; i < n; i += stride) d[i] = f2bf(s[i]);
    }
}

// ---------------------------------------------------------------------------
// hat_build: hat[b,n,k,o] = <W[n,k,o,:], inc[b,k,:]>.
// Thread owns (k, o-half): 8 W rows in VGPRs, loops 8 batches.
// No LDS, no barriers; coalesced uint4 stores (1 KB/wave per batch).
// grid (9 kc, 16 bc, 10 n) x 256.
// ---------------------------------------------------------------------------
__global__ __launch_bounds__(256) void hat_build(
    const ushort* __restrict__ icvt,   // (B, NIN, DIN) bf16
    const ushort* __restrict__ wcvt,   // (NOUTC, NIN, DOUT, DIN) bf16
    ushort* __restrict__ hatG)         // (B*NOUTC, NIN, DOUT) bf16
{
    int kc = blockIdx.x, bc = blockIdx.y, n = blockIdx.z;
    int t  = threadIdx.x;
    int k  = kc * 128 + (t >> 1);      // global k
    int oh = (t & 1) << 3;             // o offset 0 or 8

    const uint4* wp = (const uint4*)(wcvt + (((size_t)n * NIN + k) * DOUT + oh) * DIN);
    uint4 wr[8];
    #pragma unroll
    for (int j = 0; j < 8; j++) wr[j] = wp[j];

    int b0 = bc * 8;
    #pragma unroll
    for (int bl = 0; bl < 8; bl++) {
        int b = b0 + bl;
        uint4 iu = *(const uint4*)(icvt + ((size_t)b * NIN + k) * DIN);
        unsigned int h[8];
        #pragma unroll
        for (int j = 0; j < 8; j++) h[j] = f2bf(dot8(wr[j], iu));
        uint4 ov;
        ov.x = h[0] | (h[1] << 16);
        ov.y = h[2] | (h[3] << 16);
        ov.z = h[4] | (h[5] << 16);
        ov.w = h[6] | (h[7] << 16);
        *(uint4*)(hatG + (((size_t)(b * NOUTC + n) * NIN + k) * DOUT + oh)) = ov;
    }
}

// ---------------------------------------------------------------------------
// reduce_pass: one block per (b,n). Stage hat[bn] from hatG (coalesced uint4),
// rc-weighted k-sum -> squash -> outcaps; bscore[k] = <outcaps, hat_k>.
// LDS ~40 KB -> 4 blocks/CU.
// ---------------------------------------------------------------------------
__global__ __launch_bounds__(256) void reduce_pass(
    const ushort* __restrict__ hatG,     // (B*NOUTC, NIN, DOUT) bf16
    const ushort* __restrict__ cbuf,     // (B*NOUTC, NIN) bf16 coefficients
    const float*  __restrict__ rWS,      // (B*NOUTC) f32
    int iter0,
    float*  __restrict__ outcapsWS,      // (B*NOUTC, DOUT) f32
    ushort* __restrict__ bscore_out,     // (B*NOUTC, NIN) bf16 (may be null)
    void*   __restrict__ outFinal,       // final output (may be null)
    const int* __restrict__ flagp)
{
    int bn  = blockIdx.x;
    int tid = threadIdx.x;

    __shared__ uint4  hatS4[NIN * DOUT / 8];  // 36 KB
    __shared__ ushort wSb[NIN];               // 2.3 KB (bf16 rc weights)
    __shared__ float  redS[16][17];
    __shared__ float  sumS[16];
    __shared__ float  ocS[16];
    __shared__ float  scaleS;
    ushort* hatS = (ushort*)hatS4;

    const uint4* hp = (const uint4*)(hatG + (size_t)bn * NIN * DOUT);
    #pragma unroll
    for (int i = 0; i < 9; i++) hatS4[tid + 256 * i] = hp[tid + 256 * i];
    if (!iter0) {
        float rv = rWS[bn];
        for (int k = tid; k < NIN; k += 256)
            wSb[k] = f2bf(bf2f(cbuf[(size_t)bn * NIN + k]) * rv);
    }
    __syncthreads();

    // weighted sum over k: thread (g,o) sums k = g, g+16, ...
    int o16 = tid & 15, g16 = tid >> 4;
    float part = 0.f;
    for (int k = g16; k < NIN; k += 16) {
        float w = iter0 ? 1.f : bf2f(wSb[k]);
        part += w * bf2f(hatS[k * 16 + o16]);
    }
    redS[g16][o16] = part;
    __syncthreads();
    if (tid < 16) {
        float s = 0.f;
        #pragma unroll
        for (int g = 0; g < 16; g++) s += redS[g][tid];
        sumS[tid] = s;
    }
    __syncthreads();
    if (tid == 0) {
        float n2 = 0.f;
        #pragma unroll
        for (int o = 0; o < 16; o++) n2 += sumS[o] * sumS[o];
        float nrm = sqrtf(n2);
        scaleS = n2 / (1.f + n2) / (nrm + 1e-8f);
    }
    __syncthreads();
    if (tid < 16) {
        float oc = scaleS * sumS[tid];
        ocS[tid] = oc;
        outcapsWS[(size_t)bn * 16 + tid] = oc;
        if (outFinal) {
            if (*flagp) ((ushort*)outFinal)[(size_t)bn * 16 + tid] = f2bf(oc);
            else        ((float*) outFinal)[(size_t)bn * 16 + tid] = oc;
        }
    }
    __syncthreads();

    if (bscore_out) {
        for (int k = tid; k < NIN; k += 256) {
            bf16x8 h0 = ld_frag(hatS + k * 16);
            bf16x8 h1 = ld_frag(hatS + k * 16 + 8);
            float s = 0.f;
            #pragma unroll
            for (int o = 0; o < 8; o++) s += ocS[o] * (float)h0[o];
            #pragma unroll
            for (int o = 0; o < 8; o++) s += ocS[8 + o] * (float)h1[o];
            bscore_out[(size_t)bn * NIN + k] = f2bf(s);
        }
    }
}

// ---------------------------------------------------------------------------
// fallback (ws too small for hatG): round-3 COMPUTE routing pass
// ---------------------------------------------------------------------------
__global__ __launch_bounds__(256) void routing_fallback(
    const ushort* __restrict__ icvt, const ushort* __restrict__ wcvt,
    const ushort* __restrict__ cbuf, const float* __restrict__ rWS,
    int iter0, float* __restrict__ outcapsWS,
    ushort* __restrict__ bscore_out, void* __restrict__ outFinal,
    const int* __restrict__ flagp)
{
    int bn = blockIdx.x, n = bn % NOUTC, b = bn / NOUTC, tid = threadIdx.x;
    __shared__ ushort hatS[NIN * DOUT];
    __shared__ ushort incS[NIN * DIN];
    __shared__ float  wS[NIN];
    __shared__ float  redS[16][17];
    __shared__ float  sumS[16];
    __shared__ float  ocS[16];
    __shared__ float  scaleS;
    if (!iter0) {
        float rv = rWS[bn];
        for (int k = tid; k < NIN; k += 256)
            wS[k] = bf2f(cbuf[(size_t)bn * NIN + k]) * rv;
    } else {
        for (int k = tid; k < NIN; k += 256) wS[k] = 1.f;
    }
    const uint4* incp = (const uint4*)(icvt + (size_t)b * NIN * DIN);
    uint4* incS4 = (uint4*)incS;
    for (int i = tid; i < NIN * DIN / 8; i += 256) incS4[i] = incp[i];
    __syncthreads();
    const ushort* wp = wcvt + (size_t)n * NIN * DOUT * DIN;
    for (int idx = tid; idx < NIN * DOUT; idx += 256) {
        int k = idx >> 4;
        uint4 wu = *(const uint4*)(wp + (size_t)idx * 8);
        uint4 iu = *(const uint4*)(incS + k * 8);
        hatS[idx] = f2bf(dot8(wu, iu));
    }
    __syncthreads();
    int o16 = tid & 15, g16 = tid >> 4;
    float part = 0.f;
    for (int k = g16; k < NIN; k += 16)
        part += wS[k] * bf2f(hatS[k * 16 + o16]);
    redS[g16][o16] = part;
    __syncthreads();
    if (tid < 16) {
        float s = 0.f;
        #pragma unroll
        for (int g = 0; g < 16; g++) s += redS[g][tid];
        sumS[tid] = s;
    }
    __syncthreads();
    if (tid == 0) {
        float n2 = 0.f;
        #pragma unroll
        for (int o = 0; o < 16; o++) n2 += sumS[o] * sumS[o];
        float nrm = sqrtf(n2);
        scaleS = n2 / (1.f + n2) / (nrm + 1e-8f);
    }
    __syncthreads();
    if (tid < 16) {
        float oc = scaleS * sumS[tid];
        ocS[tid] = oc;
        outcapsWS[(size_t)bn * 16 + tid] = oc;
        if (outFinal) {
            if (*flagp) ((ushort*)outFinal)[(size_t)bn * 16 + tid] = f2bf(oc);
            else        ((float*) outFinal)[(size_t)bn * 16 + tid] = oc;
        }
    }
    __syncthreads();
    if (bscore_out) {
        for (int k = tid; k < NIN; k += 256) {
            bf16x8 h0 = ld_frag(hatS + k * 16);
            bf16x8 h1 = ld_frag(hatS + k * 16 + 8);
            float s = 0.f;
            #pragma unroll
            for (int o = 0; o < 8; o++) s += ocS[o] * (float)h0[o];
            #pragma unroll
            for (int o = 0; o < 8; o++) s += ocS[8 + o] * (float)h1[o];
            bscore_out[(size_t)bn * NIN + k] = f2bf(s);
        }
    }
}

// ---------------------------------------------------------------------------
// scale_coef over classes, in place on the bf16 bscore buffer. Thread per (b,k).
// ---------------------------------------------------------------------------
__global__ __launch_bounds__(256) void coef_kernel(ushort* __restrict__ cbuf)
{
    int idx = blockIdx.x * 256 + threadIdx.x;
    int b = idx / NIN, k = idx % NIN;
    ushort* col = cbuf + (size_t)b * NOUTC * NIN + k;
    float v[9], mn = 1e30f, mx = -1e30f;
    #pragma unroll
    for (int n = 0; n < 9; n++) {
        v[n] = bf2f(col[(size_t)n * NIN]);
        mn = fminf(mn, v[n]); mx = fmaxf(mx, v[n]);
    }
    float denom = fmaxf(mx - mn, 1e-6f);
    #pragma unroll
    for (int n = 0; n < 9; n++)
        col[(size_t)n * NIN] = f2bf(fmaxf((v[n] - mn) / denom, 0.5f));
    col[(size_t)9 * NIN] = f2bf(0.5f);
}

// rscore (from gemm3 partials) -> scale_coef -> r. One thread per batch elem.
__global__ __launch_bounds__(128) void r_kernel(
    const float* __restrict__ partials,  // (NROWS, 16), cols 0..nby-1 valid
    float* __restrict__ rWS, int nby)
{
    int b = threadIdx.x;
    float v[9], mn = 1e30f, mx = -1e30f;
    #pragma unroll
    for (int n = 0; n < 9; n++) {
        float s = 0.f;
        for (int j = 0; j < nby; j++)
            s += partials[(size_t)(b * NOUTC + n) * 16 + j];
        v[n] = -s;
        mn = fminf(mn, v[n]); mx = fmaxf(mx, v[n]);
    }
    float denom = fmaxf(mx - mn, 1e-6f);
    #pragma unroll
    for (int n = 0; n < 9; n++)
        rWS[b * NOUTC + n] = fmaxf((v[n] - mn) / denom, 0.5f);
    rWS[b * NOUTC + 9] = 0.5f;
}

// ---------------------------------------------------------------------------
// Decoder layer 1: masked input is block-diagonal -> 16-wide dot per row.
// ---------------------------------------------------------------------------
__global__ __launch_bounds__(128) void layer1_kernel(
    const float* __restrict__ outcapsWS, const ushort* __restrict__ W1,
    const ushort* __restrict__ b1, ushort* __restrict__ h1)
{
    int row = blockIdx.x;
    int n = row % NOUTC;
    int tid = threadIdx.x;
    __shared__ float oc[16];
    if (tid < 16) oc[tid] = outcapsWS[(size_t)row * 16 + tid];
    __syncthreads();
    for (int col = tid; col < H1DIM; col += 128) {
        float acc = bf2f(b1[col]);
        #pragma unroll
        for (int i = 0; i < 16; i++)
            acc += oc[i] * bf2f(W1[(size_t)(n * 16 + i) * H1DIM + col]);
        h1[(size_t)row * H1DIM + col] = f2bf(fmaxf(acc, 0.f));
    }
}

// ---------------------------------------------------------------------------
// tile transpose (R x C -> C x R), dtype-agnostic in, bf16 out
// ---------------------------------------------------------------------------
__global__ __launch_bounds__(256) void transpose_kernel(
    const void* __restrict__ in, const int* __restrict__ flagp,
    ushort* __restrict__ out, int R, int C)
{
    __shared__ ushort tile[32][33];
    int isbf = *flagp;
    int c0 = blockIdx.x * 32, r0 = blockIdx.y * 32;
    int tx = threadIdx.x & 31, ty = threadIdx.x >> 5;
    for (int i = ty; i < 32; i += 8) {
        int r = r0 + i, c = c0 + tx;
        tile[i][tx] = (r < R && c < C) ? f2bf(ldin(in, (size_t)r * C + c, isbf)) : (ushort)0;
    }
    __syncthreads();
    for (int i = ty; i < 32; i += 8) {
        int c = c0 + i, r = r0 + tx;
        if (c < C && r < R) out[(size_t)c * R + r] = tile[tx][i];
    }
}

// ---------------------------------------------------------------------------
// 64x64-tile MFMA GEMM: C = act(A @ Bt^T + bias).
// Cout!=null: ReLU, bf16 (layer 2). Else: fused sigmoid + squared-error vs x,
// per-block partial written to partials[row*16 + blockIdx.y] (layer 3).
// ---------------------------------------------------------------------------
__global__ __launch_bounds__(256) void gemm_kernel(
    const ushort* __restrict__ A, const ushort* __restrict__ Bt,
    const ushort* __restrict__ bias, int K, int N,
    ushort* __restrict__ Cout,
    const ushort* __restrict__ xin, float* __restrict__ partials)
{
    int m0 = blockIdx.x * 64, n0 = blockIdx.y * 64;
    int tid = threadIdx.x;
    int wave = tid >> 6, lane = tid & 63, quad = lane >> 4, l16 = lane & 15;

    __shared__ uint4 AsB[256];   // 64 x 32 bf16
    __shared__ uint4 BsB[256];   // 64 x 32 bf16 (rows of Bt)
    ushort* As = (ushort*)AsB;
    ushort* Bs = (ushort*)BsB;

    f32x4 acc[4];
    #pragma unroll
    for (int nt = 0; nt < 4; nt++)
        #pragma unroll
        for (int rg = 0; rg < 4; rg++) acc[nt][rg] = 0.f;

    int sIdx = tid * 8;
    int sMi = sIdx >> 5, sKk = sIdx & 31;

    for (int k0 = 0; k0 < K; k0 += 32) {
        *(uint4*)(As + sIdx) = *(const uint4*)(A + (size_t)(m0 + sMi) * K + k0 + sKk);
        uint4 bv = make_uint4(0, 0, 0, 0);
        if (n0 + sMi < N) bv = *(const uint4*)(Bt + (size_t)(n0 + sMi) * K + k0 + sKk);
        *(uint4*)(Bs + sIdx) = bv;
        __syncthreads();

        bf16x8 a = ld_frag(As + (wave * 16 + l16) * 32 + quad * 8);
        #pragma unroll
        for (int nt = 0; nt < 4; nt++) {
            bf16x8 bb = ld_frag(Bs + (nt * 16 + l16) * 32 + quad * 8);
            acc[nt] = __builtin_amdgcn_mfma_f32_16x16x32_bf16(a, bb, acc[nt], 0, 0, 0);
        }
        __syncthreads();
    }

    int rowBase = m0 + wave * 16 + quad * 4;
    if (Cout) {
        #pragma unroll
        for (int nt = 0; nt < 4; nt++) {
            int col = n0 + nt * 16 + l16;
            float bv = bf2f(bias[col]);
            #pragma unroll
            for (int rg = 0; rg < 4; rg++) {
                float v = acc[nt][rg] + bv;
                Cout[(size_t)(rowBase + rg) * N + col] = f2bf(fmaxf(v, 0.f));
            }
        }
    } else {
        float vr[4] = {0.f, 0.f, 0.f, 0.f};
        #pragma unroll
        for (int nt = 0; nt < 4; nt++) {
            int col = n0 + nt * 16 + l16;
            if (col < N) {
                float bv = bf2f(bias[col]);
                #pragma unroll
                for (int rg = 0; rg < 4; rg++) {
                    int row = rowBase + rg;
                    int bb = row / NOUTC;
                    float z = acc[nt][rg] + bv;
                    float s = 1.f / (1.f + __expf(-z));
                    float d = bf2f(xin[(size_t)bb * PIX + col]) - s;
                    vr[rg] += d * d;
                }
            }
        }
        #pragma unroll
        for (int rg = 0; rg < 4; rg++) {
            float v = vr[rg];
            #pragma unroll
            for (int off = 8; off >= 1; off >>= 1) v += __shfl_xor(v, off, 16);
            if (l16 == 0)
                partials[(size_t)(rowBase + rg) * 16 + blockIdx.y] = v;
        }
    }
}

// ---------------------------------------------------------------------------
extern "C" void kernel_launch(void* const* d_in, const int* in_sizes, int n_in,
                              void* d_out, int out_size, void* d_ws, size_t ws_size,
                              hipStream_t stream)
{
    const void* inc = d_in[0];   // (128,1152,8)
    const void* x   = d_in[1];   // (128,1,28,28)
    const void* w   = d_in[2];   // (10,1152,16,8)
    const void* W1  = d_in[3];   // (160,512)
    const void* b1  = d_in[4];   // (512)
    const void* W2  = d_in[5];   // (512,1024)
    const void* b2  = d_in[6];   // (1024)
    const void* W3  = d_in[7];   // (1024,784)
    const void* b3  = d_in[8];   // (784)

    char* p = (char*)d_ws;
    auto alloc = [&](size_t bytes) { void* r = p; p += (bytes + 255) & ~(size_t)255; return r; };
    int*    flagWS    = (int*)alloc(256);
    float*  outcapsWS = (float*)alloc((size_t)NROWS * 16 * 4);
    ushort* cbuf      = (ushort*)alloc((size_t)NROWS * NIN * 2);  // bscore -> c, in place
    float*  rWS       = (float*)alloc((size_t)NROWS * 4);
    float*  partials  = (float*)alloc((size_t)NROWS * 16 * 4);
    ushort* h1WS      = (ushort*)alloc((size_t)NROWS * H1DIM * 2);
    ushort* h2WS      = (ushort*)alloc((size_t)NROWS * H2DIM * 2);
    ushort* W2T       = (ushort*)alloc((size_t)H2DIM * H1DIM * 2);
    ushort* W3T       = (ushort*)alloc((size_t)PIX * H2DIM * 2);
    ushort* wcvt      = (ushort*)alloc((size_t)NOUTC * NIN * DOUT * DIN * 2);
    ushort* icvt      = (ushort*)alloc((size_t)BATCH * NIN * DIN * 2);
    ushort* W1c       = (ushort*)alloc((size_t)160 * H1DIM * 2);
    ushort* b1c       = (ushort*)alloc((size_t)H1DIM * 2);
    ushort* b2c       = (ushort*)alloc((size_t)H2DIM * 2);
    ushort* b3c       = (ushort*)alloc((size_t)PIX * 2);
    ushort* xc        = (ushort*)alloc((size_t)BATCH * PIX * 2);
    ushort* hatG      = (ushort*)alloc((size_t)NROWS * NIN * DOUT * 2);  // 47 MB, LAST
    bool haveHat = ((char*)hatG + (size_t)NROWS * NIN * DOUT * 2) <= ((char*)d_ws + ws_size);

    detect_kernel<<<1, 256, 0, stream>>>(w, flagWS);

    CvtArgs ca;
    ca.src[0] = w;   ca.dst[0] = wcvt; ca.n[0] = NOUTC * NIN * DOUT * DIN;
    ca.src[1] = inc; ca.dst[1] = icvt; ca.n[1] = BATCH * NIN * DIN;
    ca.src[2] = W1;  ca.dst[2] = W1c;  ca.n[2] = 160 * H1DIM;
    ca.src[3] = b1;  ca.dst[3] = b1c;  ca.n[3] = H1DIM;
    ca.src[4] = b2;  ca.dst[4] = b2c;  ca.n[4] = H2DIM;
    ca.src[5] = b3;  ca.dst[5] = b3c;  ca.n[5] = PIX;
    ca.src[6] = x;   ca.dst[6] = xc;   ca.n[6] = BATCH * PIX;
    cvt_all<<<dim3(96, 7), 256, 0, stream>>>(ca, flagWS);

    transpose_kernel<<<dim3(32, 16), 256, 0, stream>>>(W2, flagWS, W2T, H1DIM, H2DIM);
    transpose_kernel<<<dim3(25, 32), 256, 0, stream>>>(W3, flagWS, W3T, H2DIM, PIX);

    // routing iteration 0
    if (haveHat) {
        hat_build<<<dim3(9, 16, NOUTC), 256, 0, stream>>>(icvt, wcvt, hatG);
        reduce_pass<<<NROWS, 256, 0, stream>>>(hatG, cbuf, rWS, 1,
                                               outcapsWS, cbuf, nullptr, flagWS);
    } else {
        routing_fallback<<<NROWS, 256, 0, stream>>>(icvt, wcvt, cbuf, rWS, 1,
                                                    outcapsWS, cbuf, nullptr, flagWS);
    }

    for (int it = 0; it < 2; it++) {
        coef_kernel<<<(BATCH * NIN) / 256, 256, 0, stream>>>(cbuf);
        layer1_kernel<<<NROWS, 128, 0, stream>>>(outcapsWS, W1c, b1c, h1WS);
        gemm_kernel<<<dim3(NROWS / 64, H2DIM / 64), 256, 0, stream>>>(
            h1WS, W2T, b2c, H1DIM, H2DIM, h2WS, nullptr, nullptr);
        gemm_kernel<<<dim3(NROWS / 64, (PIX + 63) / 64), 256, 0, stream>>>(
            h2WS, W3T, b3c, H2DIM, PIX, nullptr, xc, partials);
        r_kernel<<<1, 128, 0, stream>>>(partials, rWS, (PIX + 63) / 64);

        int last = (it == 1);
        if (haveHat)
            reduce_pass<<<NROWS, 256, 0, stream>>>(hatG, cbuf, rWS, 0, outcapsWS,
                                                   last ? nullptr : cbuf,
                                                   last ? d_out : nullptr, flagWS);
        else
            routing_fallback<<<NROWS, 256, 0, stream>>>(icvt, wcvt, cbuf, rWS, 0,
                                                        outcapsWS,
                                                        last ? nullptr : cbuf,
                                                        last ? d_out : nullptr, flagWS);
    }
}

// Round 5
// 244.711 us; speedup vs baseline: 5.8412x; 1.1319x over previous
//
#include <hip/hip_runtime.h>
#include <math.h>

// Problem constants
#define BATCH  128
#define NIN    1152
#define DIN    8
#define NOUTC  10
#define DOUT   16
#define H1DIM  512
#define H2DIM  1024
#define PIX    784
#define NROWS  (BATCH * NOUTC)   // 1280
#define NBY3   13                // ceil(784/64) col-tiles in gemm3

typedef __attribute__((ext_vector_type(8))) __bf16 bf16x8;
typedef __attribute__((ext_vector_type(4))) float  f32x4;

__device__ __forceinline__ float bf2f(unsigned int u) {
    union { unsigned int i; float f; } v; v.i = u << 16; return v.f;
}
__device__ __forceinline__ ushort f2bf(float f) {
    union { float f; unsigned int i; } v; v.f = f;
    unsigned int r = v.i + 0x7FFFu + ((v.i >> 16) & 1u);
    return (ushort)(r >> 16);
}
__device__ __forceinline__ float ldin(const void* p, size_t i, int isbf) {
    return isbf ? bf2f(((const ushort*)p)[i]) : ((const float*)p)[i];
}
__device__ __forceinline__ bf16x8 ld_frag(const ushort* p) {
    uint4 u = *(const uint4*)p;
    return __builtin_bit_cast(bf16x8, u);
}
// dot product of two packed-bf16x8 uint4s, fp32 accum
__device__ __forceinline__ float dot8(uint4 a, uint4 b) {
    float s;
    s  = bf2f(a.x & 0xffffu) * bf2f(b.x & 0xffffu);
    s += bf2f(a.x >> 16)     * bf2f(b.x >> 16);
    s += bf2f(a.y & 0xffffu) * bf2f(b.y & 0xffffu);
    s += bf2f(a.y >> 16)     * bf2f(b.y >> 16);
    s += bf2f(a.z & 0xffffu) * bf2f(b.z & 0xffffu);
    s += bf2f(a.z >> 16)     * bf2f(b.z >> 16);
    s += bf2f(a.w & 0xffffu) * bf2f(b.w & 0xffffu);
    s += bf2f(a.w >> 16)     * bf2f(b.w >> 16);
    return s;
}

// ---------------------------------------------------------------------------
// dtype probe (bf16 vs f32 inputs)
// ---------------------------------------------------------------------------
__global__ __launch_bounds__(256) void detect_kernel(const void* w, int* flag)
{
    __shared__ int cnt;
    if (threadIdx.x == 0) cnt = 0;
    __syncthreads();
    const ushort* u = (const ushort*)w;
    int c = 0;
    for (int s = threadIdx.x; s < 512; s += 256) {
        int e = (u[s * 2] >> 7) & 0xFF;
        if (e >= 88 && e <= 140) c++;
    }
    atomicAdd(&cnt, c);
    __syncthreads();
    if (threadIdx.x == 0) *flag = (cnt >= 384) ? 1 : 0;
}

// ---------------------------------------------------------------------------
// fused dtype normalization of all 7 small tensors (one launch)
// ---------------------------------------------------------------------------
struct CvtArgs { const void* src[7]; ushort* dst[7]; int n[7]; };

__global__ __launch_bounds__(256) void cvt_all(CvtArgs a, const int* __restrict__ flagp)
{
    int seg = blockIdx.y;
    int isbf = *flagp;
    int n = a.n[seg];
    int stride = gridDim.x * 256;
    int i0 = blockIdx.x * 256 + threadIdx.x;
    if (isbf) {
        const ushort* s = (const ushort*)a.src[seg];
        ushort* d = a.dst[seg];
        for (int i = i0; i < n; i += stride) d[i] = s[i];
    } else {
        const float* s = (const float*)a.src[seg];
        ushort* d = a.dst[seg];
        for (int i = i0; i < n; i += stride) d[i] = f2bf(s[i]);
    }
}

// ---------------------------------------------------------------------------
// hat_build: hat[b,n,k,o] = <W[n,k,o,:], inc[b,k,:]>.
// Thread owns (k, o-half): 8 W rows in VGPRs, loops 8 batches. No LDS/barriers.
// ---------------------------------------------------------------------------
__global__ __launch_bounds__(256) void hat_build(
    const ushort* __restrict__ icvt,   // (B, NIN, DIN) bf16
    const ushort* __restrict__ wcvt,   // (NOUTC, NIN, DOUT, DIN) bf16
    ushort* __restrict__ hatG)         // (B*NOUTC, NIN, DOUT) bf16
{
    int kc = blockIdx.x, bc = blockIdx.y, n = blockIdx.z;
    int t  = threadIdx.x;
    int k  = kc * 128 + (t >> 1);
    int oh = (t & 1) << 3;

    const uint4* wp = (const uint4*)(wcvt + (((size_t)n * NIN + k) * DOUT + oh) * DIN);
    uint4 wr[8];
    #pragma unroll
    for (int j = 0; j < 8; j++) wr[j] = wp[j];

    int b0 = bc * 8;
    #pragma unroll
    for (int bl = 0; bl < 8; bl++) {
        int b = b0 + bl;
        uint4 iu = *(const uint4*)(icvt + ((size_t)b * NIN + k) * DIN);
        unsigned int h[8];
        #pragma unroll
        for (int j = 0; j < 8; j++) h[j] = f2bf(dot8(wr[j], iu));
        uint4 ov;
        ov.x = h[0] | (h[1] << 16);
        ov.y = h[2] | (h[3] << 16);
        ov.z = h[4] | (h[5] << 16);
        ov.w = h[6] | (h[7] << 16);
        *(uint4*)(hatG + (((size_t)(b * NOUTC + n) * NIN + k) * DOUT + oh)) = ov;
    }
}

// ---------------------------------------------------------------------------
// reduce_pass: one block per (b,n). Fuses: scale_coef(c) from prev bscore,
// scale_coef(r) from gemm3 partials, rc-weighted k-sum, squash, bscore,
// decoder layer-1 (block-diagonal). COMPUTE=true recomputes hat in LDS
// (fallback when ws lacks room for hatG); else stages hat from hatG.
// ---------------------------------------------------------------------------
template<bool COMPUTE>
__global__ __launch_bounds__(256) void reduce_pass(
    const ushort* __restrict__ hatG,     // (B*NOUTC, NIN, DOUT) bf16
    const ushort* __restrict__ icvt,     // COMPUTE only
    const ushort* __restrict__ wcvt,     // COMPUTE only
    const ushort* __restrict__ bsPrev,   // (B*NOUTC, NIN) bf16 prev bscore
    const float*  __restrict__ partials, // (NROWS,16) gemm3 partials
    int iter0,
    float*  __restrict__ outcapsWS,      // (B*NOUTC, DOUT) f32
    const ushort* __restrict__ W1c,      // (160, 512) bf16
    const ushort* __restrict__ b1c,      // (512) bf16
    ushort* __restrict__ h1out,          // (B*NOUTC, 512) bf16 (may be null)
    ushort* __restrict__ bsOut,          // (B*NOUTC, NIN) bf16 (may be null)
    void*   __restrict__ outFinal,       // final output (may be null)
    const int* __restrict__ flagp)
{
    int bn  = blockIdx.x;
    int n   = bn % NOUTC;
    int b   = bn / NOUTC;
    int tid = threadIdx.x;

    __shared__ uint4  hatS4[NIN * DOUT / 8];  // 36 KB
    __shared__ float  wS[NIN];                // 4.6 KB
    __shared__ float  redS[16][17];
    __shared__ float  sumS[16];
    __shared__ float  ocS[16];
    __shared__ float  scaleS;
    ushort* hatS = (ushort*)hatS4;

    if (COMPUTE) {
        __shared__ uint4 incS4[NIN * DIN / 8];
        const uint4* incp = (const uint4*)(icvt + (size_t)b * NIN * DIN);
        for (int i = tid; i < NIN * DIN / 8; i += 256) incS4[i] = incp[i];
        // rc weights (c from prev bscore, r from partials) while inc stages
        if (!iter0) {
            float v[9], mn = 1e30f, mx = -1e30f;
            #pragma unroll
            for (int n2 = 0; n2 < 9; n2++) {
                float s = 0.f;
                for (int j = 0; j < NBY3; j++)
                    s += partials[(size_t)(b * NOUTC + n2) * 16 + j];
                v[n2] = -s;
                mn = fminf(mn, v[n2]); mx = fmaxf(mx, v[n2]);
            }
            float den = fmaxf(mx - mn, 1e-6f);
            float rv = (n < 9) ? fmaxf((v[n] - mn) / den, 0.5f) : 0.5f;
            for (int k = tid; k < NIN; k += 256) {
                float c = 0.5f;
                if (n < 9) {
                    float vv[9], mn2 = 1e30f, mx2 = -1e30f;
                    #pragma unroll
                    for (int n2 = 0; n2 < 9; n2++) {
                        vv[n2] = bf2f(bsPrev[(size_t)(b * NOUTC + n2) * NIN + k]);
                        mn2 = fminf(mn2, vv[n2]); mx2 = fmaxf(mx2, vv[n2]);
                    }
                    float den2 = fmaxf(mx2 - mn2, 1e-6f);
                    c = fmaxf((vv[n] - mn2) / den2, 0.5f);
                }
                wS[k] = c * rv;
            }
        }
        __syncthreads();
        const ushort* incS = (const ushort*)incS4;
        const ushort* wp = wcvt + (size_t)n * NIN * DOUT * DIN;
        for (int idx = tid; idx < NIN * DOUT; idx += 256) {
            int k = idx >> 4;
            uint4 wu = *(const uint4*)(wp + (size_t)idx * 8);
            uint4 iu = *(const uint4*)(incS + k * 8);
            hatS[idx] = f2bf(dot8(wu, iu));
        }
        __syncthreads();
    } else {
        const uint4* hp = (const uint4*)(hatG + (size_t)bn * NIN * DOUT);
        #pragma unroll
        for (int i = 0; i < 9; i++) hatS4[tid + 256 * i] = hp[tid + 256 * i];
        if (!iter0) {
            float v[9], mn = 1e30f, mx = -1e30f;
            #pragma unroll
            for (int n2 = 0; n2 < 9; n2++) {
                float s = 0.f;
                for (int j = 0; j < NBY3; j++)
                    s += partials[(size_t)(b * NOUTC + n2) * 16 + j];
                v[n2] = -s;
                mn = fminf(mn, v[n2]); mx = fmaxf(mx, v[n2]);
            }
            float den = fmaxf(mx - mn, 1e-6f);
            float rv = (n < 9) ? fmaxf((v[n] - mn) / den, 0.5f) : 0.5f;
            for (int k = tid; k < NIN; k += 256) {
                float c = 0.5f;
                if (n < 9) {
                    float vv[9], mn2 = 1e30f, mx2 = -1e30f;
                    #pragma unroll
                    for (int n2 = 0; n2 < 9; n2++) {
                        vv[n2] = bf2f(bsPrev[(size_t)(b * NOUTC + n2) * NIN + k]);
                        mn2 = fminf(mn2, vv[n2]); mx2 = fmaxf(mx2, vv[n2]);
                    }
                    float den2 = fmaxf(mx2 - mn2, 1e-6f);
                    c = fmaxf((vv[n] - mn2) / den2, 0.5f);
                }
                wS[k] = c * rv;
            }
        }
        __syncthreads();
    }

    // weighted sum over k: thread (g,o) sums k = g, g+16, ...
    int o16 = tid & 15, g16 = tid >> 4;
    float part = 0.f;
    for (int k = g16; k < NIN; k += 16) {
        float w = iter0 ? 1.f : wS[k];
        part += w * bf2f(hatS[k * 16 + o16]);
    }
    redS[g16][o16] = part;
    __syncthreads();
    if (tid < 16) {
        float s = 0.f;
        #pragma unroll
        for (int g = 0; g < 16; g++) s += redS[g][tid];
        sumS[tid] = s;
    }
    __syncthreads();
    if (tid == 0) {
        float n2 = 0.f;
        #pragma unroll
        for (int o = 0; o < 16; o++) n2 += sumS[o] * sumS[o];
        float nrm = sqrtf(n2);
        scaleS = n2 / (1.f + n2) / (nrm + 1e-8f);
    }
    __syncthreads();
    if (tid < 16) {
        float oc = scaleS * sumS[tid];
        ocS[tid] = oc;
        outcapsWS[(size_t)bn * 16 + tid] = oc;
        if (outFinal) {
            if (*flagp) ((ushort*)outFinal)[(size_t)bn * 16 + tid] = f2bf(oc);
            else        ((float*) outFinal)[(size_t)bn * 16 + tid] = oc;
        }
    }
    __syncthreads();

    if (bsOut) {
        for (int k = tid; k < NIN; k += 256) {
            bf16x8 h0 = ld_frag(hatS + k * 16);
            bf16x8 h1 = ld_frag(hatS + k * 16 + 8);
            float s = 0.f;
            #pragma unroll
            for (int o = 0; o < 8; o++) s += ocS[o] * (float)h0[o];
            #pragma unroll
            for (int o = 0; o < 8; o++) s += ocS[8 + o] * (float)h1[o];
            bsOut[(size_t)bn * NIN + k] = f2bf(s);
        }
    }

    // fused decoder layer 1 (block-diagonal): h1[bn, col]
    if (h1out) {
        for (int col = tid; col < H1DIM; col += 256) {
            float acc = bf2f(b1c[col]);
            #pragma unroll
            for (int i = 0; i < 16; i++)
                acc += ocS[i] * bf2f(W1c[(size_t)(n * 16 + i) * H1DIM + col]);
            h1out[(size_t)bn * H1DIM + col] = f2bf(fmaxf(acc, 0.f));
        }
    }
}

// ---------------------------------------------------------------------------
// tile transpose (R x C -> C x R), dtype-agnostic in, bf16 out
// ---------------------------------------------------------------------------
__global__ __launch_bounds__(256) void transpose_kernel(
    const void* __restrict__ in, const int* __restrict__ flagp,
    ushort* __restrict__ out, int R, int C)
{
    __shared__ ushort tile[32][33];
    int isbf = *flagp;
    int c0 = blockIdx.x * 32, r0 = blockIdx.y * 32;
    int tx = threadIdx.x & 31, ty = threadIdx.x >> 5;
    for (int i = ty; i < 32; i += 8) {
        int r = r0 + i, c = c0 + tx;
        tile[i][tx] = (r < R && c < C) ? f2bf(ldin(in, (size_t)r * C + c, isbf)) : (ushort)0;
    }
    __syncthreads();
    for (int i = ty; i < 32; i += 8) {
        int c = c0 + i, r = r0 + tx;
        if (c < C && r < R) out[(size_t)c * R + r] = tile[tx][i];
    }
}

// ---------------------------------------------------------------------------
// 64x64-tile MFMA GEMM: C = act(A @ Bt^T + bias).
// Cout!=null: ReLU, bf16 (layer 2). Else: fused sigmoid + squared-error vs x,
// per-block partial -> partials[row*16 + blockIdx.y] (layer 3).
// ---------------------------------------------------------------------------
__global__ __launch_bounds__(256) void gemm_kernel(
    const ushort* __restrict__ A, const ushort* __restrict__ Bt,
    const ushort* __restrict__ bias, int K, int N,
    ushort* __restrict__ Cout,
    const ushort* __restrict__ xin, float* __restrict__ partials)
{
    int m0 = blockIdx.x * 64, n0 = blockIdx.y * 64;
    int tid = threadIdx.x;
    int wave = tid >> 6, lane = tid & 63, quad = lane >> 4, l16 = lane & 15;

    __shared__ uint4 AsB[256];   // 64 x 32 bf16
    __shared__ uint4 BsB[256];   // 64 x 32 bf16 (rows of Bt)
    ushort* As = (ushort*)AsB;
    ushort* Bs = (ushort*)BsB;

    f32x4 acc[4];
    #pragma unroll
    for (int nt = 0; nt < 4; nt++)
        #pragma unroll
        for (int rg = 0; rg < 4; rg++) acc[nt][rg] = 0.f;

    int sIdx = tid * 8;
    int sMi = sIdx >> 5, sKk = sIdx & 31;

    for (int k0 = 0; k0 < K; k0 += 32) {
        *(uint4*)(As + sIdx) = *(const uint4*)(A + (size_t)(m0 + sMi) * K + k0 + sKk);
        uint4 bv = make_uint4(0, 0, 0, 0);
        if (n0 + sMi < N) bv = *(const uint4*)(Bt + (size_t)(n0 + sMi) * K + k0 + sKk);
        *(uint4*)(Bs + sIdx) = bv;
        __syncthreads();

        bf16x8 a = ld_frag(As + (wave * 16 + l16) * 32 + quad * 8);
        #pragma unroll
        for (int nt = 0; nt < 4; nt++) {
            bf16x8 bb = ld_frag(Bs + (nt * 16 + l16) * 32 + quad * 8);
            acc[nt] = __builtin_amdgcn_mfma_f32_16x16x32_bf16(a, bb, acc[nt], 0, 0, 0);
        }
        __syncthreads();
    }

    int rowBase = m0 + wave * 16 + quad * 4;
    if (Cout) {
        #pragma unroll
        for (int nt = 0; nt < 4; nt++) {
            int col = n0 + nt * 16 + l16;
            float bv = bf2f(bias[col]);
            #pragma unroll
            for (int rg = 0; rg < 4; rg++) {
                float v = acc[nt][rg] + bv;
                Cout[(size_t)(rowBase + rg) * N + col] = f2bf(fmaxf(v, 0.f));
            }
        }
    } else {
        float vr[4] = {0.f, 0.f, 0.f, 0.f};
        #pragma unroll
        for (int nt = 0; nt < 4; nt++) {
            int col = n0 + nt * 16 + l16;
            if (col < N) {
                float bv = bf2f(bias[col]);
                #pragma unroll
                for (int rg = 0; rg < 4; rg++) {
                    int row = rowBase + rg;
                    int bb = row / NOUTC;
                    float z = acc[nt][rg] + bv;
                    float s = 1.f / (1.f + __expf(-z));
                    float d = bf2f(xin[(size_t)bb * PIX + col]) - s;
                    vr[rg] += d * d;
                }
            }
        }
        #pragma unroll
        for (int rg = 0; rg < 4; rg++) {
            float v = vr[rg];
            #pragma unroll
            for (int off = 8; off >= 1; off >>= 1) v += __shfl_xor(v, off, 16);
            if (l16 == 0)
                partials[(size_t)(rowBase + rg) * 16 + blockIdx.y] = v;
        }
    }
}

// ---------------------------------------------------------------------------
extern "C" void kernel_launch(void* const* d_in, const int* in_sizes, int n_in,
                              void* d_out, int out_size, void* d_ws, size_t ws_size,
                              hipStream_t stream)
{
    const void* inc = d_in[0];   // (128,1152,8)
    const void* x   = d_in[1];   // (128,1,28,28)
    const void* w   = d_in[2];   // (10,1152,16,8)
    const void* W1  = d_in[3];   // (160,512)
    const void* b1  = d_in[4];   // (512)
    const void* W2  = d_in[5];   // (512,1024)
    const void* b2  = d_in[6];   // (1024)
    const void* W3  = d_in[7];   // (1024,784)
    const void* b3  = d_in[8];   // (784)

    char* p = (char*)d_ws;
    auto alloc = [&](size_t bytes) { void* r = p; p += (bytes + 255) & ~(size_t)255; return r; };
    int*    flagWS    = (int*)alloc(256);
    float*  outcapsWS = (float*)alloc((size_t)NROWS * 16 * 4);
    ushort* bsA       = (ushort*)alloc((size_t)NROWS * NIN * 2);
    ushort* bsB       = (ushort*)alloc((size_t)NROWS * NIN * 2);
    float*  partials  = (float*)alloc((size_t)NROWS * 16 * 4);
    ushort* h1WS      = (ushort*)alloc((size_t)NROWS * H1DIM * 2);
    ushort* h2WS      = (ushort*)alloc((size_t)NROWS * H2DIM * 2);
    ushort* W2T       = (ushort*)alloc((size_t)H2DIM * H1DIM * 2);
    ushort* W3T       = (ushort*)alloc((size_t)PIX * H2DIM * 2);
    ushort* wcvt      = (ushort*)alloc((size_t)NOUTC * NIN * DOUT * DIN * 2);
    ushort* icvt      = (ushort*)alloc((size_t)BATCH * NIN * DIN * 2);
    ushort* W1c       = (ushort*)alloc((size_t)160 * H1DIM * 2);
    ushort* b1c       = (ushort*)alloc((size_t)H1DIM * 2);
    ushort* b2c       = (ushort*)alloc((size_t)H2DIM * 2);
    ushort* b3c       = (ushort*)alloc((size_t)PIX * 2);
    ushort* xc        = (ushort*)alloc((size_t)BATCH * PIX * 2);
    ushort* hatG      = (ushort*)alloc((size_t)NROWS * NIN * DOUT * 2);  // 47 MB, LAST
    bool haveHat = ((char*)hatG + (size_t)NROWS * NIN * DOUT * 2) <= ((char*)d_ws + ws_size);

    detect_kernel<<<1, 256, 0, stream>>>(w, flagWS);

    CvtArgs ca;
    ca.src[0] = w;   ca.dst[0] = wcvt; ca.n[0] = NOUTC * NIN * DOUT * DIN;
    ca.src[1] = inc; ca.dst[1] = icvt; ca.n[1] = BATCH * NIN * DIN;
    ca.src[2] = W1;  ca.dst[2] = W1c;  ca.n[2] = 160 * H1DIM;
    ca.src[3] = b1;  ca.dst[3] = b1c;  ca.n[3] = H1DIM;
    ca.src[4] = b2;  ca.dst[4] = b2c;  ca.n[4] = H2DIM;
    ca.src[5] = b3;  ca.dst[5] = b3c;  ca.n[5] = PIX;
    ca.src[6] = x;   ca.dst[6] = xc;   ca.n[6] = BATCH * PIX;
    cvt_all<<<dim3(96, 7), 256, 0, stream>>>(ca, flagWS);

    transpose_kernel<<<dim3(32, 16), 256, 0, stream>>>(W2, flagWS, W2T, H1DIM, H2DIM);
    transpose_kernel<<<dim3(25, 32), 256, 0, stream>>>(W3, flagWS, W3T, H2DIM, PIX);

    if (haveHat) hat_build<<<dim3(9, 16, NOUTC), 256, 0, stream>>>(icvt, wcvt, hatG);

    // iter 0: rc = 1; writes bscore->bsA and fused layer-1 h1
    if (haveHat)
        reduce_pass<false><<<NROWS, 256, 0, stream>>>(
            hatG, icvt, wcvt, nullptr, nullptr, 1, outcapsWS,
            W1c, b1c, h1WS, bsA, nullptr, flagWS);
    else
        reduce_pass<true><<<NROWS, 256, 0, stream>>>(
            nullptr, icvt, wcvt, nullptr, nullptr, 1, outcapsWS,
            W1c, b1c, h1WS, bsA, nullptr, flagWS);

    for (int it = 0; it < 2; it++) {
        gemm_kernel<<<dim3(NROWS / 64, H2DIM / 64), 256, 0, stream>>>(
            h1WS, W2T, b2c, H1DIM, H2DIM, h2WS, nullptr, nullptr);
        gemm_kernel<<<dim3(NROWS / 64, NBY3), 256, 0, stream>>>(
            h2WS, W3T, b3c, H2DIM, PIX, nullptr, xc, partials);

        int last = (it == 1);
        const ushort* bsP = (it == 0) ? bsA : bsB;
        ushort* bsO       = last ? nullptr : bsB;
        ushort* h1o       = last ? nullptr : h1WS;
        void*   fin       = last ? d_out : nullptr;
        if (haveHat)
            reduce_pass<false><<<NROWS, 256, 0, stream>>>(
                hatG, icvt, wcvt, bsP, partials, 0, outcapsWS,
                W1c, b1c, h1o, bsO, fin, flagWS);
        else
            reduce_pass<true><<<NROWS, 256, 0, stream>>>(
                nullptr, icvt, wcvt, bsP, partials, 0, outcapsWS,
                W1c, b1c, h1o, bsO, fin, flagWS);
    }
}

// Round 6
// 229.923 us; speedup vs baseline: 6.2169x; 1.0643x over previous
//
#include <hip/hip_runtime.h>
#include <math.h>

// Problem constants
#define BATCH  128
#define NIN    1152
#define DIN    8
#define NOUTC  10
#define DOUT   16
#define H1DIM  512
#define H2DIM  1024
#define PIX    784
#define NROWS  (BATCH * NOUTC)   // 1280
#define NBY3   13                // ceil(784/64) col-tiles in gemm3

typedef __attribute__((ext_vector_type(8))) __bf16 bf16x8;
typedef __attribute__((ext_vector_type(4))) float  f32x4;

__device__ __forceinline__ float bf2f(unsigned int u) {
    union { unsigned int i; float f; } v; v.i = u << 16; return v.f;
}
__device__ __forceinline__ ushort f2bf(float f) {
    union { float f; unsigned int i; } v; v.f = f;
    unsigned int r = v.i + 0x7FFFu + ((v.i >> 16) & 1u);
    return (ushort)(r >> 16);
}
__device__ __forceinline__ float ldin(const void* p, size_t i, int isbf) {
    return isbf ? bf2f(((const ushort*)p)[i]) : ((const float*)p)[i];
}
__device__ __forceinline__ bf16x8 ld_frag(const ushort* p) {
    uint4 u = *(const uint4*)p;
    return __builtin_bit_cast(bf16x8, u);
}
// dot product of two packed-bf16x8 uint4s, fp32 accum
__device__ __forceinline__ float dot8(uint4 a, uint4 b) {
    float s;
    s  = bf2f(a.x & 0xffffu) * bf2f(b.x & 0xffffu);
    s += bf2f(a.x >> 16)     * bf2f(b.x >> 16);
    s += bf2f(a.y & 0xffffu) * bf2f(b.y & 0xffffu);
    s += bf2f(a.y >> 16)     * bf2f(b.y >> 16);
    s += bf2f(a.z & 0xffffu) * bf2f(b.z & 0xffffu);
    s += bf2f(a.z >> 16)     * bf2f(b.z >> 16);
    s += bf2f(a.w & 0xffffu) * bf2f(b.w & 0xffffu);
    s += bf2f(a.w >> 16)     * bf2f(b.w >> 16);
    return s;
}

// ---------------------------------------------------------------------------
// prep: one launch does dtype detect + all bf16 conversions + both weight
// transposes. Segments on blockIdx.y: 0..6 = cvt tensors, 7 = W2^T, 8 = W3^T.
// Each block computes the dtype flag locally (1 KB of w, L2-broadcast);
// block (0,0) publishes it for later kernels.
// ---------------------------------------------------------------------------
struct PrepArgs {
    const void* src[9];   // 0:w 1:inc 2:W1 3:b1 4:b2 5:b3 6:x 7:W2 8:W3
    ushort*     dst[9];
    int         n[9];     // element counts for segs 0..6
    int*        flag;
};

__global__ __launch_bounds__(256) void prep_kernel(PrepArgs a)
{
    __shared__ int cntS;
    __shared__ ushort tile[32][33];
    int tid = threadIdx.x;
    if (tid == 0) cntS = 0;
    __syncthreads();
    // local dtype detect on w
    {
        const ushort* wu = (const ushort*)a.src[0];
        int c = 0;
        for (int s = tid; s < 512; s += 256) {
            int e = (wu[s * 2] >> 7) & 0xFF;
            if (e >= 88 && e <= 140) c++;
        }
        atomicAdd(&cntS, c);
    }
    __syncthreads();
    int isbf = (cntS >= 384) ? 1 : 0;
    int seg = blockIdx.y;
    if (seg == 0 && blockIdx.x == 0 && tid == 0) *a.flag = isbf;

    if (seg <= 6) {
        int n = a.n[seg];
        int stride = gridDim.x * 256;
        ushort* d = a.dst[seg];
        if (isbf) {
            const ushort* s = (const ushort*)a.src[seg];
            for (int i = blockIdx.x * 256 + tid; i < n; i += stride) d[i] = s[i];
        } else {
            const float* s = (const float*)a.src[seg];
            for (int i = blockIdx.x * 256 + tid; i < n; i += stride) d[i] = f2bf(s[i]);
        }
        return;
    }
    // transposes: seg 7 = W2 (512x1024), seg 8 = W3 (1024x784)
    int R = (seg == 7) ? H1DIM : H2DIM;
    int C = (seg == 7) ? H2DIM : PIX;
    int tilesX = (seg == 7) ? 32 : 25;
    int tilesY = (seg == 7) ? 16 : 32;
    int t = blockIdx.x;
    if (t >= tilesX * tilesY) return;
    int tx2 = t % tilesX, ty2 = t / tilesX;
    int c0 = tx2 * 32, r0 = ty2 * 32;
    const void* in = a.src[seg];
    ushort* out = a.dst[seg];
    int tx = tid & 31, ty = tid >> 5;
    for (int i = ty; i < 32; i += 8) {
        int r = r0 + i, c = c0 + tx;
        tile[i][tx] = (r < R && c < C) ? f2bf(ldin(in, (size_t)r * C + c, isbf)) : (ushort)0;
    }
    __syncthreads();
    for (int i = ty; i < 32; i += 8) {
        int c = c0 + i, r = r0 + tx;
        if (c < C && r < R) out[(size_t)c * R + r] = tile[tx][i];
    }
}

// ---------------------------------------------------------------------------
// hat_build: hat[b,n,k,o] = <W[n,k,o,:], inc[b,k,:]>.
// Thread owns (k, o-half): 8 W rows live in VGPRs, loops 16 batches.
// grid (9 kc, 8 bc, 10 n) x 256 = 720 blocks. No LDS / barriers.
// ---------------------------------------------------------------------------
__global__ __launch_bounds__(256) void hat_build(
    const ushort* __restrict__ icvt,   // (B, NIN, DIN) bf16
    const ushort* __restrict__ wcvt,   // (NOUTC, NIN, DOUT, DIN) bf16
    ushort* __restrict__ hatG)         // (B*NOUTC, NIN, DOUT) bf16
{
    int kc = blockIdx.x, bc = blockIdx.y, n = blockIdx.z;
    int t  = threadIdx.x;
    int k  = kc * 128 + (t >> 1);
    int oh = (t & 1) << 3;

    const uint4* wp = (const uint4*)(wcvt + (((size_t)n * NIN + k) * DOUT + oh) * DIN);
    uint4 wr[8];
    #pragma unroll
    for (int j = 0; j < 8; j++) wr[j] = wp[j];

    int b0 = bc * 16;
    #pragma unroll 4
    for (int bl = 0; bl < 16; bl++) {
        int b = b0 + bl;
        uint4 iu = *(const uint4*)(icvt + ((size_t)b * NIN + k) * DIN);
        unsigned int h[8];
        #pragma unroll
        for (int j = 0; j < 8; j++) h[j] = f2bf(dot8(wr[j], iu));
        uint4 ov;
        ov.x = h[0] | (h[1] << 16);
        ov.y = h[2] | (h[3] << 16);
        ov.z = h[4] | (h[5] << 16);
        ov.w = h[6] | (h[7] << 16);
        *(uint4*)(hatG + (((size_t)(b * NOUTC + n) * NIN + k) * DOUT + oh)) = ov;
    }
}

// ---------------------------------------------------------------------------
// reduce_pass: one block per (b,n). Fuses scale_coef(c), scale_coef(r),
// rc-weighted k-sum, squash, bscore, decoder layer-1.
// Parity decomposition: thread t owns hat row (t>>1), o-half (t&1) -> all hat
// LDS traffic is conflict-free ds_read_b128. LDS ~39.5 KB -> 4 blocks/CU.
// ---------------------------------------------------------------------------
template<bool COMPUTE>
__global__ __launch_bounds__(256) void reduce_pass(
    const ushort* __restrict__ hatG,
    const ushort* __restrict__ icvt,
    const ushort* __restrict__ wcvt,
    const ushort* __restrict__ bsPrev,   // (B*NOUTC, NIN) bf16 prev bscore
    const float*  __restrict__ partials, // (NROWS,16) gemm3 partials
    int iter0,
    float*  __restrict__ outcapsWS,
    const ushort* __restrict__ W1c,      // (160, 512) bf16
    const ushort* __restrict__ b1c,      // (512) bf16
    ushort* __restrict__ h1out,          // (B*NOUTC, 512) bf16 (may be null)
    ushort* __restrict__ bsOut,          // (B*NOUTC, NIN) bf16 (may be null)
    void*   __restrict__ outFinal,       // final output (may be null)
    const int* __restrict__ flagp)
{
    int bn  = blockIdx.x;
    int n   = bn % NOUTC;
    int b   = bn / NOUTC;
    int tid = threadIdx.x;

    __shared__ uint4  hatS4[NIN * DOUT / 8];  // 36 KB
    __shared__ ushort wSb[NIN];               // 2.3 KB bf16 rc weights
    __shared__ float  redS[4][16];
    __shared__ float  sumS[16];
    __shared__ float  ocS[16];
    __shared__ float  scaleS;
    ushort* hatS = (ushort*)hatS4;

    if constexpr (COMPUTE) {
        __shared__ uint4 incS4[NIN * DIN / 8];
        const uint4* incp = (const uint4*)(icvt + (size_t)b * NIN * DIN);
        for (int i = tid; i < NIN * DIN / 8; i += 256) incS4[i] = incp[i];
        if (!iter0) {
            float v[9], mn = 1e30f, mx = -1e30f;
            #pragma unroll
            for (int n2 = 0; n2 < 9; n2++) {
                float s = 0.f;
                for (int j = 0; j < NBY3; j++)
                    s += partials[(size_t)(b * NOUTC + n2) * 16 + j];
                v[n2] = -s;
                mn = fminf(mn, v[n2]); mx = fmaxf(mx, v[n2]);
            }
            float den = fmaxf(mx - mn, 1e-6f);
            float rv = (n < 9) ? fmaxf((v[n] - mn) / den, 0.5f) : 0.5f;
            for (int k = tid; k < NIN; k += 256) {
                float c = 0.5f;
                if (n < 9) {
                    float vv[9], mn2 = 1e30f, mx2 = -1e30f;
                    #pragma unroll
                    for (int n2 = 0; n2 < 9; n2++) {
                        vv[n2] = bf2f(bsPrev[(size_t)(b * NOUTC + n2) * NIN + k]);
                        mn2 = fminf(mn2, vv[n2]); mx2 = fmaxf(mx2, vv[n2]);
                    }
                    float den2 = fmaxf(mx2 - mn2, 1e-6f);
                    c = fmaxf((vv[n] - mn2) / den2, 0.5f);
                }
                wSb[k] = f2bf(c * rv);
            }
        }
        __syncthreads();
        const ushort* incS = (const ushort*)incS4;
        const ushort* wp = wcvt + (size_t)n * NIN * DOUT * DIN;
        for (int idx = tid; idx < NIN * DOUT; idx += 256) {
            int k = idx >> 4;
            uint4 wu = *(const uint4*)(wp + (size_t)idx * 8);
            uint4 iu = *(const uint4*)(incS + k * 8);
            hatS[idx] = f2bf(dot8(wu, iu));
        }
        __syncthreads();
    } else {
        const uint4* hp = (const uint4*)(hatG + (size_t)bn * NIN * DOUT);
        #pragma unroll
        for (int i = 0; i < 9; i++) hatS4[tid + 256 * i] = hp[tid + 256 * i];
        if (!iter0) {
            float v[9], mn = 1e30f, mx = -1e30f;
            #pragma unroll
            for (int n2 = 0; n2 < 9; n2++) {
                float s = 0.f;
                for (int j = 0; j < NBY3; j++)
                    s += partials[(size_t)(b * NOUTC + n2) * 16 + j];
                v[n2] = -s;
                mn = fminf(mn, v[n2]); mx = fmaxf(mx, v[n2]);
            }
            float den = fmaxf(mx - mn, 1e-6f);
            float rv = (n < 9) ? fmaxf((v[n] - mn) / den, 0.5f) : 0.5f;
            for (int k = tid; k < NIN; k += 256) {
                float c = 0.5f;
                if (n < 9) {
                    float vv[9], mn2 = 1e30f, mx2 = -1e30f;
                    #pragma unroll
                    for (int n2 = 0; n2 < 9; n2++) {
                        vv[n2] = bf2f(bsPrev[(size_t)(b * NOUTC + n2) * NIN + k]);
                        mn2 = fminf(mn2, vv[n2]); mx2 = fmaxf(mx2, vv[n2]);
                    }
                    float den2 = fmaxf(mx2 - mn2, 1e-6f);
                    c = fmaxf((vv[n] - mn2) / den2, 0.5f);
                }
                wSb[k] = f2bf(c * rv);
            }
        }
        __syncthreads();
    }

    // weighted k-sum, parity decomposition: thread owns row kb = tid>>1,
    // o-half h = tid&1; conflict-free ds_read_b128.
    int h = tid & 1, kb = tid >> 1;
    int wave = tid >> 6, lane = tid & 63;
    float acc[8];
    #pragma unroll
    for (int o = 0; o < 8; o++) acc[o] = 0.f;
    #pragma unroll
    for (int j = 0; j < 9; j++) {
        int k = kb + 128 * j;
        float w = iter0 ? 1.f : bf2f(wSb[k]);
        bf16x8 hv = ld_frag(hatS + k * 16 + h * 8);
        #pragma unroll
        for (int o = 0; o < 8; o++) acc[o] += w * (float)hv[o];
    }
    // reduce across same-parity lanes (offsets 2..32), keeping h partition
    #pragma unroll
    for (int off = 32; off >= 2; off >>= 1) {
        #pragma unroll
        for (int o = 0; o < 8; o++) acc[o] += __shfl_xor(acc[o], off);
    }
    if (lane < 2) {
        #pragma unroll
        for (int o = 0; o < 8; o++) redS[wave][lane * 8 + o] = acc[o];
    }
    __syncthreads();
    if (tid < 16)
        sumS[tid] = redS[0][tid] + redS[1][tid] + redS[2][tid] + redS[3][tid];
    __syncthreads();
    if (tid == 0) {
        float n2 = 0.f;
        #pragma unroll
        for (int o = 0; o < 16; o++) n2 += sumS[o] * sumS[o];
        float nrm = sqrtf(n2);
        scaleS = n2 / (1.f + n2) / (nrm + 1e-8f);
    }
    __syncthreads();
    if (tid < 16) {
        float oc = scaleS * sumS[tid];
        ocS[tid] = oc;
        outcapsWS[(size_t)bn * 16 + tid] = oc;
        if (outFinal) {
            if (*flagp) ((ushort*)outFinal)[(size_t)bn * 16 + tid] = f2bf(oc);
            else        ((float*) outFinal)[(size_t)bn * 16 + tid] = oc;
        }
    }
    __syncthreads();

    // bscore: same parity decomposition, pairwise shuffle to combine halves
    if (bsOut) {
        #pragma unroll
        for (int j = 0; j < 9; j++) {
            int k = kb + 128 * j;
            bf16x8 hv = ld_frag(hatS + k * 16 + h * 8);
            float s = 0.f;
            #pragma unroll
            for (int o = 0; o < 8; o++) s += ocS[h * 8 + o] * (float)hv[o];
            s += __shfl_xor(s, 1);
            if (h == 0) bsOut[(size_t)bn * NIN + k] = f2bf(s);
        }
    }

    // fused decoder layer 1 (block-diagonal): h1[bn, col]
    if (h1out) {
        for (int col = tid; col < H1DIM; col += 256) {
            float acc1 = bf2f(b1c[col]);
            #pragma unroll
            for (int i = 0; i < 16; i++)
                acc1 += ocS[i] * bf2f(W1c[(size_t)(n * 16 + i) * H1DIM + col]);
            h1out[(size_t)bn * H1DIM + col] = f2bf(fmaxf(acc1, 0.f));
        }
    }
}

// ---------------------------------------------------------------------------
// 64x64-tile MFMA GEMM with register double-buffered staging.
// Cout!=null: ReLU, bf16 (layer 2). Else: fused sigmoid + squared-error vs x,
// per-block partial -> partials[row*16 + blockIdx.y] (layer 3).
// ---------------------------------------------------------------------------
__global__ __launch_bounds__(256) void gemm_kernel(
    const ushort* __restrict__ A, const ushort* __restrict__ Bt,
    const ushort* __restrict__ bias, int K, int N,
    ushort* __restrict__ Cout,
    const ushort* __restrict__ xin, float* __restrict__ partials)
{
    int m0 = blockIdx.x * 64, n0 = blockIdx.y * 64;
    int tid = threadIdx.x;
    int wave = tid >> 6, lane = tid & 63, quad = lane >> 4, l16 = lane & 15;

    __shared__ uint4 As4[256];   // 64 x 32 bf16
    __shared__ uint4 Bs4[256];   // 64 x 32 bf16 (rows of Bt)
    ushort* As = (ushort*)As4;
    ushort* Bs = (ushort*)Bs4;

    f32x4 acc[4];
    #pragma unroll
    for (int nt = 0; nt < 4; nt++)
        #pragma unroll
        for (int rg = 0; rg < 4; rg++) acc[nt][rg] = 0.f;

    int sMi = tid >> 2, sKk = (tid & 3) * 8;
    const ushort* Ap = A + (size_t)(m0 + sMi) * K + sKk;
    const ushort* Bp = Bt + (size_t)(n0 + sMi) * K + sKk;
    bool bOK = (n0 + sMi) < N;

    uint4 aR = *(const uint4*)Ap;
    uint4 bR = bOK ? *(const uint4*)Bp : make_uint4(0, 0, 0, 0);

    for (int k0 = 0; k0 < K; k0 += 32) {
        As4[tid] = aR;
        Bs4[tid] = bR;
        __syncthreads();
        if (k0 + 32 < K) {  // prefetch next tile while MFMAs run
            aR = *(const uint4*)(Ap + k0 + 32);
            bR = bOK ? *(const uint4*)(Bp + k0 + 32) : make_uint4(0, 0, 0, 0);
        }
        bf16x8 a = ld_frag(As + (wave * 16 + l16) * 32 + quad * 8);
        #pragma unroll
        for (int nt = 0; nt < 4; nt++) {
            bf16x8 bb = ld_frag(Bs + (nt * 16 + l16) * 32 + quad * 8);
            acc[nt] = __builtin_amdgcn_mfma_f32_16x16x32_bf16(a, bb, acc[nt], 0, 0, 0);
        }
        __syncthreads();
    }

    int rowBase = m0 + wave * 16 + quad * 4;
    if (Cout) {
        #pragma unroll
        for (int nt = 0; nt < 4; nt++) {
            int col = n0 + nt * 16 + l16;
            float bv = bf2f(bias[col]);
            #pragma unroll
            for (int rg = 0; rg < 4; rg++) {
                float v = acc[nt][rg] + bv;
                Cout[(size_t)(rowBase + rg) * N + col] = f2bf(fmaxf(v, 0.f));
            }
        }
    } else {
        float vr[4] = {0.f, 0.f, 0.f, 0.f};
        #pragma unroll
        for (int nt = 0; nt < 4; nt++) {
            int col = n0 + nt * 16 + l16;
            if (col < N) {
                float bv = bf2f(bias[col]);
                #pragma unroll
                for (int rg = 0; rg < 4; rg++) {
                    int row = rowBase + rg;
                    int bb = row / NOUTC;
                    float z = acc[nt][rg] + bv;
                    float s = 1.f / (1.f + __expf(-z));
                    float d = bf2f(xin[(size_t)bb * PIX + col]) - s;
                    vr[rg] += d * d;
                }
            }
        }
        #pragma unroll
        for (int rg = 0; rg < 4; rg++) {
            float v = vr[rg];
            #pragma unroll
            for (int off = 8; off >= 1; off >>= 1) v += __shfl_xor(v, off, 16);
            if (l16 == 0)
                partials[(size_t)(rowBase + rg) * 16 + blockIdx.y] = v;
        }
    }
}

// ---------------------------------------------------------------------------
extern "C" void kernel_launch(void* const* d_in, const int* in_sizes, int n_in,
                              void* d_out, int out_size, void* d_ws, size_t ws_size,
                              hipStream_t stream)
{
    const void* inc = d_in[0];   // (128,1152,8)
    const void* x   = d_in[1];   // (128,1,28,28)
    const void* w   = d_in[2];   // (10,1152,16,8)
    const void* W1  = d_in[3];   // (160,512)
    const void* b1  = d_in[4];   // (512)
    const void* W2  = d_in[5];   // (512,1024)
    const void* b2  = d_in[6];   // (1024)
    const void* W3  = d_in[7];   // (1024,784)
    const void* b3  = d_in[8];   // (784)

    char* p = (char*)d_ws;
    auto alloc = [&](size_t bytes) { void* r = p; p += (bytes + 255) & ~(size_t)255; return r; };
    int*    flagWS    = (int*)alloc(256);
    float*  outcapsWS = (float*)alloc((size_t)NROWS * 16 * 4);
    ushort* bsA       = (ushort*)alloc((size_t)NROWS * NIN * 2);
    ushort* bsB       = (ushort*)alloc((size_t)NROWS * NIN * 2);
    float*  partials  = (float*)alloc((size_t)NROWS * 16 * 4);
    ushort* h1WS      = (ushort*)alloc((size_t)NROWS * H1DIM * 2);
    ushort* h2WS      = (ushort*)alloc((size_t)NROWS * H2DIM * 2);
    ushort* W2T       = (ushort*)alloc((size_t)H2DIM * H1DIM * 2);
    ushort* W3T       = (ushort*)alloc((size_t)PIX * H2DIM * 2);
    ushort* wcvt      = (ushort*)alloc((size_t)NOUTC * NIN * DOUT * DIN * 2);
    ushort* icvt      = (ushort*)alloc((size_t)BATCH * NIN * DIN * 2);
    ushort* W1c       = (ushort*)alloc((size_t)160 * H1DIM * 2);
    ushort* b1c       = (ushort*)alloc((size_t)H1DIM * 2);
    ushort* b2c       = (ushort*)alloc((size_t)H2DIM * 2);
    ushort* b3c       = (ushort*)alloc((size_t)PIX * 2);
    ushort* xc        = (ushort*)alloc((size_t)BATCH * PIX * 2);
    ushort* hatG      = (ushort*)alloc((size_t)NROWS * NIN * DOUT * 2);  // 47 MB, LAST
    bool haveHat = ((char*)hatG + (size_t)NROWS * NIN * DOUT * 2) <= ((char*)d_ws + ws_size);

    PrepArgs pa;
    pa.src[0] = w;   pa.dst[0] = wcvt; pa.n[0] = NOUTC * NIN * DOUT * DIN;
    pa.src[1] = inc; pa.dst[1] = icvt; pa.n[1] = BATCH * NIN * DIN;
    pa.src[2] = W1;  pa.dst[2] = W1c;  pa.n[2] = 160 * H1DIM;
    pa.src[3] = b1;  pa.dst[3] = b1c;  pa.n[3] = H1DIM;
    pa.src[4] = b2;  pa.dst[4] = b2c;  pa.n[4] = H2DIM;
    pa.src[5] = b3;  pa.dst[5] = b3c;  pa.n[5] = PIX;
    pa.src[6] = x;   pa.dst[6] = xc;   pa.n[6] = BATCH * PIX;
    pa.src[7] = W2;  pa.dst[7] = W2T;  pa.n[7] = 0;
    pa.src[8] = W3;  pa.dst[8] = W3T;  pa.n[8] = 0;
    pa.flag = flagWS;
    prep_kernel<<<dim3(800, 9), 256, 0, stream>>>(pa);

    if (haveHat) hat_build<<<dim3(9, 8, NOUTC), 256, 0, stream>>>(icvt, wcvt, hatG);

    // iter 0: rc = 1; writes bscore->bsA and fused layer-1 h1
    if (haveHat)
        reduce_pass<false><<<NROWS, 256, 0, stream>>>(
            hatG, icvt, wcvt, nullptr, nullptr, 1, outcapsWS,
            W1c, b1c, h1WS, bsA, nullptr, flagWS);
    else
        reduce_pass<true><<<NROWS, 256, 0, stream>>>(
            nullptr, icvt, wcvt, nullptr, nullptr, 1, outcapsWS,
            W1c, b1c, h1WS, bsA, nullptr, flagWS);

    for (int it = 0; it < 2; it++) {
        gemm_kernel<<<dim3(NROWS / 64, H2DIM / 64), 256, 0, stream>>>(
            h1WS, W2T, b2c, H1DIM, H2DIM, h2WS, nullptr, nullptr);
        gemm_kernel<<<dim3(NROWS / 64, NBY3), 256, 0, stream>>>(
            h2WS, W3T, b3c, H2DIM, PIX, nullptr, xc, partials);

        int last = (it == 1);
        const ushort* bsP = (it == 0) ? bsA : bsB;
        ushort* bsO       = last ? nullptr : bsB;
        ushort* h1o       = last ? nullptr : h1WS;
        void*   fin       = last ? d_out : nullptr;
        if (haveHat)
            reduce_pass<false><<<NROWS, 256, 0, stream>>>(
                hatG, icvt, wcvt, bsP, partials, 0, outcapsWS,
                W1c, b1c, h1o, bsO, fin, flagWS);
        else
            reduce_pass<true><<<NROWS, 256, 0, stream>>>(
                nullptr, icvt, wcvt, bsP, partials, 0, outcapsWS,
                W1c, b1c, h1o, bsO, fin, flagWS);
    }
}